// Round 1
// baseline (2127.032 us; speedup 1.0000x reference)
//
#include <hip/hip_runtime.h>

#define B_TOT 2048
#define T_LEN 512
#define IN0   9
#define H     56
#define NG    224              // 4*H gates
#define BG    8                // batch per block
#define NTH   512
#define NBLK  (B_TOT / BG)     // 256 blocks

#define WHH_FLOATS (NG * H)    // 12544 floats per 224x56 matrix

// LDS float totals
#define LDS_BIG_FLOATS   40096   // 3 matrices + biases + h dbuf + y   = 160384 B
#define LDS_SMALL_FLOATS 15008   // 1 matrix + biases + h dbuf + y     =  60032 B

__device__ __forceinline__ float rcp_f(float v)  { return __builtin_amdgcn_rcpf(v); }
__device__ __forceinline__ float sigm_f(float v) { return rcp_f(1.0f + __expf(-v)); }
__device__ __forceinline__ float tanh_f(float v) { return 1.0f - 2.0f * rcp_f(1.0f + __expf(2.0f * v)); }

#define FMA4(acc, wv, vv) \
  acc = fmaf((wv).x, (vv).x, acc); acc = fmaf((wv).y, (vv).y, acc); \
  acc = fmaf((wv).z, (vv).z, acc); acc = fmaf((wv).w, (vv).w, acc)

template<bool BIG>
__global__ __launch_bounds__(NTH, 2)
void lstm_all(const float* __restrict__ x,
              const float* __restrict__ w_ih0, const float* __restrict__ w_hh0,
              const float* __restrict__ b_ih0, const float* __restrict__ b_hh0,
              const float* __restrict__ w_ih1, const float* __restrict__ w_hh1,
              const float* __restrict__ b_ih1, const float* __restrict__ b_hh1,
              const float* __restrict__ fc1_w, const float* __restrict__ fc1_b,
              const float* __restrict__ fc2_w, const float* __restrict__ fc2_b,
              float* __restrict__ out)
{
  extern __shared__ float lds[];
  constexpr int OFF_WIH1 = WHH_FLOATS;                       // BIG only
  constexpr int OFF_WHH1 = 2 * WHH_FLOATS;                   // BIG only
  constexpr int OFF_B0   = BIG ? 3 * WHH_FLOATS : WHH_FLOATS;
  constexpr int OFF_B1   = OFF_B0 + NG;
  constexpr int OFF_H0   = OFF_B1 + NG;                      // [2][BG][H]
  constexpr int OFF_H1   = OFF_H0 + 2 * BG * H;              // [2][BG][H]
  constexpr int OFF_Y    = OFF_H1 + 2 * BG * H;              // [BG][28]

  const int tid = threadIdx.x;

  // ---- stage weights / biases into LDS, zero h state ----
  for (int i = tid; i < WHH_FLOATS / 4; i += NTH)
    ((float4*)(lds))[i] = ((const float4*)w_hh0)[i];
  if (BIG) {
    for (int i = tid; i < WHH_FLOATS / 4; i += NTH)
      ((float4*)(lds + OFF_WIH1))[i] = ((const float4*)w_ih1)[i];
    for (int i = tid; i < WHH_FLOATS / 4; i += NTH)
      ((float4*)(lds + OFF_WHH1))[i] = ((const float4*)w_hh1)[i];
  }
  for (int i = tid; i < NG; i += NTH) {
    lds[OFF_B0 + i] = b_ih0[i] + b_hh0[i];
    lds[OFF_B1 + i] = b_ih1[i] + b_hh1[i];
  }
  for (int i = tid; i < 4 * BG * H; i += NTH)
    lds[OFF_H0 + i] = 0.0f;

  const int j = tid >> 3;        // hidden unit 0..63 (active < 56)
  const int b = tid & 7;         // batch within block
  const bool act = (j < H);
  const int jj = act ? j : 0;

  // w_ih0 rows (i,f,g,o) for this j live in registers for the whole kernel
  float wi0[4][IN0];
  if (act) {
    #pragma unroll
    for (int g = 0; g < 4; ++g)
      #pragma unroll
      for (int k = 0; k < IN0; ++k)
        wi0[g][k] = w_ih0[(g * H + j) * IN0 + k];
  }

  __syncthreads();

  float bi0 = 0.f, bf0 = 0.f, bg0 = 0.f, bo0 = 0.f;
  float bi1 = 0.f, bf1 = 0.f, bg1 = 0.f, bo1 = 0.f;
  if (act) {
    bi0 = lds[OFF_B0 + j];         bf0 = lds[OFF_B0 + H + j];
    bg0 = lds[OFF_B0 + 2 * H + j]; bo0 = lds[OFF_B0 + 3 * H + j];
    bi1 = lds[OFF_B1 + j];         bf1 = lds[OFF_B1 + H + j];
    bg1 = lds[OFF_B1 + 2 * H + j]; bo1 = lds[OFF_B1 + 3 * H + j];
  }

  const float* Wih1 = BIG ? (lds + OFF_WIH1) : w_ih1;
  const float* Whh1 = BIG ? (lds + OFF_WHH1) : w_hh1;

  const float4* w0i  = (const float4*)(lds  + (0 * H + jj) * H);
  const float4* w0f  = (const float4*)(lds  + (1 * H + jj) * H);
  const float4* w0g  = (const float4*)(lds  + (2 * H + jj) * H);
  const float4* w0o  = (const float4*)(lds  + (3 * H + jj) * H);
  const float4* w1ii = (const float4*)(Wih1 + (0 * H + jj) * H);
  const float4* w1if = (const float4*)(Wih1 + (1 * H + jj) * H);
  const float4* w1ig = (const float4*)(Wih1 + (2 * H + jj) * H);
  const float4* w1io = (const float4*)(Wih1 + (3 * H + jj) * H);
  const float4* w1hi = (const float4*)(Whh1 + (0 * H + jj) * H);
  const float4* w1hf = (const float4*)(Whh1 + (1 * H + jj) * H);
  const float4* w1hg = (const float4*)(Whh1 + (2 * H + jj) * H);
  const float4* w1ho = (const float4*)(Whh1 + (3 * H + jj) * H);

  float* sH0 = lds + OFF_H0;
  float* sH1 = lds + OFF_H1;

  float c0 = 0.f, c1 = 0.f;
  const float* xp = x + (size_t)(blockIdx.x * BG + b) * T_LEN * IN0;

  float xc[IN0];
  if (act) {
    #pragma unroll
    for (int k = 0; k < IN0; ++k) xc[k] = xp[k];
  }

  for (int t = 0; t < T_LEN; ++t) {
    const int rr = t & 1;        // read parity
    const int ww = rr ^ 1;       // write parity

    // prefetch next timestep's x into registers
    float xn[IN0];
    const bool more = (t + 1 < T_LEN);
    if (act && more) {
      #pragma unroll
      for (int k = 0; k < IN0; ++k) xn[k] = xp[IN0 + k];
    }

    // -------- layer 0 --------
    if (act) {
      float ai = bi0, af = bf0, ag = bg0, ao = bo0;
      #pragma unroll
      for (int k = 0; k < IN0; ++k) {
        const float xv = xc[k];
        ai = fmaf(wi0[0][k], xv, ai);
        af = fmaf(wi0[1][k], xv, af);
        ag = fmaf(wi0[2][k], xv, ag);
        ao = fmaf(wi0[3][k], xv, ao);
      }
      const float4* hv4 = (const float4*)(sH0 + (rr * BG + b) * H);
      #pragma unroll
      for (int q = 0; q < H / 4; ++q) {
        const float4 h4 = hv4[q];
        float4 wv;
        wv = w0i[q]; FMA4(ai, wv, h4);
        wv = w0f[q]; FMA4(af, wv, h4);
        wv = w0g[q]; FMA4(ag, wv, h4);
        wv = w0o[q]; FMA4(ao, wv, h4);
      }
      const float iv = sigm_f(ai);
      const float fv = sigm_f(af);
      const float gv = tanh_f(ag);
      const float ov = sigm_f(ao);
      c0 = fmaf(fv, c0, iv * gv);
      sH0[(ww * BG + b) * H + j] = ov * tanh_f(c0);
    }
    __syncthreads();   // the single per-timestep barrier (hazards verified)

    // -------- layer 1 (input = fresh h0) --------
    if (act) {
      float ai = bi1, af = bf1, ag = bg1, ao = bo1;
      const float4* uv4 = (const float4*)(sH0 + (ww * BG + b) * H);
      const float4* hv4 = (const float4*)(sH1 + (rr * BG + b) * H);
      #pragma unroll
      for (int q = 0; q < H / 4; ++q) {
        const float4 u4 = uv4[q];
        const float4 h4 = hv4[q];
        float4 wv;
        wv = w1ii[q]; FMA4(ai, wv, u4);
        wv = w1hi[q]; FMA4(ai, wv, h4);
        wv = w1if[q]; FMA4(af, wv, u4);
        wv = w1hf[q]; FMA4(af, wv, h4);
        wv = w1ig[q]; FMA4(ag, wv, u4);
        wv = w1hg[q]; FMA4(ag, wv, h4);
        wv = w1io[q]; FMA4(ao, wv, u4);
        wv = w1ho[q]; FMA4(ao, wv, h4);
      }
      const float iv = sigm_f(ai);
      const float fv = sigm_f(af);
      const float gv = tanh_f(ag);
      const float ov = sigm_f(ao);
      c1 = fmaf(fv, c1, iv * gv);
      sH1[(ww * BG + b) * H + j] = ov * tanh_f(c1);

      if (more) {
        #pragma unroll
        for (int k = 0; k < IN0; ++k) xc[k] = xn[k];
      }
    }
    xp += IN0;
  }
  __syncthreads();

  // -------- FC head on h1[:, T-1] (final parity after t=511 is buffer 0) --------
  if (tid < 28 * BG) {
    const int m  = tid >> 3;     // 0..27
    const int bb = tid & 7;
    const float4* h4p = (const float4*)(sH1 + bb * H);
    const float4* w4  = (const float4*)(fc1_w + m * H);
    float acc = fc1_b[m];
    #pragma unroll
    for (int q = 0; q < H / 4; ++q) {
      const float4 wv = w4[q], hv = h4p[q];
      FMA4(acc, wv, hv);
    }
    lds[OFF_Y + bb * 28 + m] = fmaxf(acc, 0.0f);
  }
  __syncthreads();
  if (tid < BG) {
    float acc = fc2_b[0];
    #pragma unroll
    for (int m = 0; m < 28; ++m)
      acc = fmaf(fc2_w[m], lds[OFF_Y + tid * 28 + m], acc);
    out[blockIdx.x * BG + tid] = acc;
  }
}

extern "C" void kernel_launch(void* const* d_in, const int* in_sizes, int n_in,
                              void* d_out, int out_size, void* d_ws, size_t ws_size,
                              hipStream_t stream)
{
  const float* x     = (const float*)d_in[0];
  const float* w_ih0 = (const float*)d_in[1];
  const float* w_hh0 = (const float*)d_in[2];
  const float* b_ih0 = (const float*)d_in[3];
  const float* b_hh0 = (const float*)d_in[4];
  const float* w_ih1 = (const float*)d_in[5];
  const float* w_hh1 = (const float*)d_in[6];
  const float* b_ih1 = (const float*)d_in[7];
  const float* b_hh1 = (const float*)d_in[8];
  const float* fc1_w = (const float*)d_in[9];
  const float* fc1_b = (const float*)d_in[10];
  const float* fc2_w = (const float*)d_in[11];
  const float* fc2_b = (const float*)d_in[12];
  float* out = (float*)d_out;

  const size_t SHM_BIG   = (size_t)LDS_BIG_FLOATS * sizeof(float);    // 160384 B
  const size_t SHM_SMALL = (size_t)LDS_SMALL_FLOATS * sizeof(float);  //  60032 B

  // Decide whether the 160 KB all-weights-in-LDS path is available.
  // (Pure host queries / attribute set: not stream ops, capture-safe.)
  int dev = 0;
  (void)hipGetDevice(&dev);
  int shmax = 0;
  (void)hipDeviceGetAttribute(&shmax, hipDeviceAttributeMaxSharedMemoryPerBlock, dev);
  hipError_t attr_rc = hipFuncSetAttribute(
      reinterpret_cast<const void*>(lstm_all<true>),
      hipFuncAttributeMaxDynamicSharedMemorySize, (int)SHM_BIG);
  const bool big = (shmax >= (int)SHM_BIG) || (attr_rc == hipSuccess);

  if (big) {
    lstm_all<true><<<NBLK, NTH, SHM_BIG, stream>>>(
        x, w_ih0, w_hh0, b_ih0, b_hh0, w_ih1, w_hh1, b_ih1, b_hh1,
        fc1_w, fc1_b, fc2_w, fc2_b, out);
  } else {
    lstm_all<false><<<NBLK, NTH, SHM_SMALL, stream>>>(
        x, w_ih0, w_hh0, b_ih0, b_hh0, w_ih1, w_hh1, b_ih1, b_hh1,
        fc1_w, fc1_b, fc2_w, fc2_b, out);
  }
}

// Round 3
// 2083.155 us; speedup vs baseline: 1.0211x; 1.0211x over previous
//
#include <hip/hip_runtime.h>

#define B_TOT 2048
#define T_LEN 512
#define IN0   9
#define H     56
#define NG    224              // 4*H gates
#define BG    8                // batch per block
#define NTH   1024             // (j 0..63) x (s 0..1) x (b 0..7)
#define NBLK  (B_TOT / BG)     // 256 blocks

#define WHH_FLOATS (NG * H)    // 12544 floats per 224x56 matrix

// LDS float totals
#define LDS_BIG_FLOATS   40096   // 3 matrices + biases + h dbuf + y = 160384 B
#define LDS_SMALL_FLOATS 15008   // 1 matrix + biases + h dbuf + y   =  60032 B

__device__ __forceinline__ float rcp_f(float v)  { return __builtin_amdgcn_rcpf(v); }
__device__ __forceinline__ float sigm_f(float v) { return rcp_f(1.0f + __expf(-v)); }
__device__ __forceinline__ float tanh_f(float v) { return 1.0f - 2.0f * rcp_f(1.0f + __expf(2.0f * v)); }

#define FMA4(acc, wv, vv) \
  acc = fmaf((wv).x, (vv).x, acc); acc = fmaf((wv).y, (vv).y, acc); \
  acc = fmaf((wv).z, (vv).z, acc); acc = fmaf((wv).w, (vv).w, acc)

template<bool BIG>
__global__ __launch_bounds__(NTH, 4)
void lstm_all(const float* __restrict__ x,
              const float* __restrict__ w_ih0, const float* __restrict__ w_hh0,
              const float* __restrict__ b_ih0, const float* __restrict__ b_hh0,
              const float* __restrict__ w_ih1, const float* __restrict__ w_hh1,
              const float* __restrict__ b_ih1, const float* __restrict__ b_hh1,
              const float* __restrict__ fc1_w, const float* __restrict__ fc1_b,
              const float* __restrict__ fc2_w, const float* __restrict__ fc2_b,
              float* __restrict__ out)
{
  extern __shared__ float lds[];
  constexpr int OFF_WIH1 = WHH_FLOATS;                       // BIG only
  constexpr int OFF_WHH1 = 2 * WHH_FLOATS;                   // BIG only
  constexpr int OFF_B0   = BIG ? 3 * WHH_FLOATS : WHH_FLOATS;
  constexpr int OFF_B1   = OFF_B0 + NG;
  constexpr int OFF_H0   = OFF_B1 + NG;                      // [2][BG][H]
  constexpr int OFF_H1   = OFF_H0 + 2 * BG * H;              // [2][BG][H]
  constexpr int OFF_Y    = OFF_H1 + 2 * BG * H;              // [BG][28]

  const int tid = threadIdx.x;

  // ---- stage weights / biases into LDS, zero h state ----
  for (int i = tid; i < WHH_FLOATS / 4; i += NTH)
    ((float4*)(lds))[i] = ((const float4*)w_hh0)[i];
  if (BIG) {
    for (int i = tid; i < WHH_FLOATS / 4; i += NTH)
      ((float4*)(lds + OFF_WIH1))[i] = ((const float4*)w_ih1)[i];
    for (int i = tid; i < WHH_FLOATS / 4; i += NTH)
      ((float4*)(lds + OFF_WHH1))[i] = ((const float4*)w_hh1)[i];
  }
  for (int i = tid; i < NG; i += NTH) {
    lds[OFF_B0 + i] = b_ih0[i] + b_hh0[i];
    lds[OFF_B1 + i] = b_ih1[i] + b_hh1[i];
  }
  for (int i = tid; i < 4 * BG * H; i += NTH)
    lds[OFF_H0 + i] = 0.0f;

  // thread decomposition: waves 0..13 fully j-active, 14..15 run harmlessly
  const int j = tid >> 4;          // hidden unit 0..63 (active < 56)
  const int s = (tid >> 3) & 1;    // which half of the dot products
  const int b = tid & 7;           // batch within block
  const bool act = (j < H);
  const int jj = act ? j : 0;      // clamped for safe addressing
  const int s7 = s * 7;            // float4 offset into the 14-float4 row

  // x-dot split: s==0 -> k in [0,5), s==1 -> k in [5,9) (5th slot zero-padded)
  float wih[4][5];
  #pragma unroll
  for (int g = 0; g < 4; ++g) {
    #pragma unroll
    for (int kk = 0; kk < 5; ++kk) {
      const int idx = s * 5 + kk;
      const int ci  = (idx > 8) ? 8 : idx;          // clamp: always in-bounds
      const float wv = w_ih0[(g * H + jj) * IN0 + ci];
      wih[g][kk] = (act && idx < 9) ? wv : 0.0f;    // per-lane-constant select
    }
  }

  __syncthreads();

  // biases: s==0 half carries them (select, not branch)
  const float ssel = (s == 0) ? 1.0f : 0.0f;
  const float bi0 = lds[OFF_B0 + jj] * ssel;
  const float bf0 = lds[OFF_B0 + H + jj] * ssel;
  const float bg0 = lds[OFF_B0 + 2 * H + jj] * ssel;
  const float bo0 = lds[OFF_B0 + 3 * H + jj] * ssel;
  const float bi1 = lds[OFF_B1 + jj] * ssel;
  const float bf1 = lds[OFF_B1 + H + jj] * ssel;
  const float bg1 = lds[OFF_B1 + 2 * H + jj] * ssel;
  const float bo1 = lds[OFF_B1 + 3 * H + jj] * ssel;

  const float* Wih1 = BIG ? (lds + OFF_WIH1) : w_ih1;
  const float* Whh1 = BIG ? (lds + OFF_WHH1) : w_hh1;

  // per-thread half-row weight pointers (7 float4 each)
  const float4* w0i  = (const float4*)(lds  + (0 * H + jj) * H) + s7;
  const float4* w0f  = (const float4*)(lds  + (1 * H + jj) * H) + s7;
  const float4* w0g  = (const float4*)(lds  + (2 * H + jj) * H) + s7;
  const float4* w0o  = (const float4*)(lds  + (3 * H + jj) * H) + s7;
  const float4* w1ii = (const float4*)(Wih1 + (0 * H + jj) * H) + s7;
  const float4* w1if = (const float4*)(Wih1 + (1 * H + jj) * H) + s7;
  const float4* w1ig = (const float4*)(Wih1 + (2 * H + jj) * H) + s7;
  const float4* w1io = (const float4*)(Wih1 + (3 * H + jj) * H) + s7;
  const float4* w1hi = (const float4*)(Whh1 + (0 * H + jj) * H) + s7;
  const float4* w1hf = (const float4*)(Whh1 + (1 * H + jj) * H) + s7;
  const float4* w1hg = (const float4*)(Whh1 + (2 * H + jj) * H) + s7;
  const float4* w1ho = (const float4*)(Whh1 + (3 * H + jj) * H) + s7;

  float* sH0 = lds + OFF_H0;
  float* sH1 = lds + OFF_H1;

  float c0 = 0.f, c1 = 0.f;
  const float* xp = x + (size_t)(blockIdx.x * BG + b) * T_LEN * IN0;

  // clamped x indices for this half (5th slot of s==1 is a dummy, weight=0)
  int cidx[5];
  #pragma unroll
  for (int kk = 0; kk < 5; ++kk) {
    const int idx = s * 5 + kk;
    cidx[kk] = (idx > 8) ? 8 : idx;
  }

  float xh[5];
  #pragma unroll
  for (int kk = 0; kk < 5; ++kk) xh[kk] = xp[cidx[kk]];

  for (int t = 0; t < T_LEN; ++t) {
    const int rr = t & 1;        // read parity
    const int ww = rr ^ 1;       // write parity
    const bool more = (t + 1 < T_LEN);   // wave-uniform

    // prefetch next timestep's x (uniform branch)
    float xn[5];
    if (more) {
      #pragma unroll
      for (int kk = 0; kk < 5; ++kk) xn[kk] = xp[IN0 + cidx[kk]];
    }

    // -------- layer 0 (NO lane-divergent flow before the shuffles) --------
    {
      float ai = bi0, af = bf0, ag = bg0, ao = bo0;
      #pragma unroll
      for (int kk = 0; kk < 5; ++kk) {
        const float xv = xh[kk];
        ai = fmaf(wih[0][kk], xv, ai);
        af = fmaf(wih[1][kk], xv, af);
        ag = fmaf(wih[2][kk], xv, ag);
        ao = fmaf(wih[3][kk], xv, ao);
      }
      const float4* hv4 = (const float4*)(sH0 + (rr * BG + b) * H) + s7;
      #pragma unroll
      for (int q = 0; q < 7; ++q) {
        const float4 h4 = hv4[q];
        float4 wv;
        wv = w0i[q]; FMA4(ai, wv, h4);
        wv = w0f[q]; FMA4(af, wv, h4);
        wv = w0g[q]; FMA4(ag, wv, h4);
        wv = w0o[q]; FMA4(ao, wv, h4);
      }
      // combine halves — executed in uniform control flow
      ai += __shfl_xor(ai, 8);
      af += __shfl_xor(af, 8);
      ag += __shfl_xor(ag, 8);
      ao += __shfl_xor(ao, 8);
      const float iv = sigm_f(ai);
      const float fv = sigm_f(af);
      const float gv = tanh_f(ag);
      const float ov = sigm_f(ao);
      c0 = fmaf(fv, c0, iv * gv);
      const float h0v = ov * tanh_f(c0);
      if (act && s == 0) sH0[(ww * BG + b) * H + j] = h0v;  // diverge AFTER shuffles
    }
    __syncthreads();   // the single per-timestep barrier

    // -------- layer 1 (input = fresh h0) --------
    {
      float ai = bi1, af = bf1, ag = bg1, ao = bo1;
      const float4* uv4 = (const float4*)(sH0 + (ww * BG + b) * H) + s7;
      const float4* hv4 = (const float4*)(sH1 + (rr * BG + b) * H) + s7;
      #pragma unroll
      for (int q = 0; q < 7; ++q) {
        const float4 u4 = uv4[q];
        const float4 h4 = hv4[q];
        float4 wv;
        wv = w1ii[q]; FMA4(ai, wv, u4);
        wv = w1hi[q]; FMA4(ai, wv, h4);
        wv = w1if[q]; FMA4(af, wv, u4);
        wv = w1hf[q]; FMA4(af, wv, h4);
        wv = w1ig[q]; FMA4(ag, wv, u4);
        wv = w1hg[q]; FMA4(ag, wv, h4);
        wv = w1io[q]; FMA4(ao, wv, u4);
        wv = w1ho[q]; FMA4(ao, wv, h4);
      }
      ai += __shfl_xor(ai, 8);
      af += __shfl_xor(af, 8);
      ag += __shfl_xor(ag, 8);
      ao += __shfl_xor(ao, 8);
      const float iv = sigm_f(ai);
      const float fv = sigm_f(af);
      const float gv = tanh_f(ag);
      const float ov = sigm_f(ao);
      c1 = fmaf(fv, c1, iv * gv);
      const float h1v = ov * tanh_f(c1);
      if (act && s == 0) sH1[(ww * BG + b) * H + j] = h1v;
    }

    // uniform register copies
    if (more) {
      #pragma unroll
      for (int kk = 0; kk < 5; ++kk) xh[kk] = xn[kk];
    }
    xp += IN0;
  }
  __syncthreads();

  // -------- FC head on h1[:, T-1] (final parity after t=511 is buffer 0) ----
  if (tid < 28 * BG) {
    const int m  = tid >> 3;     // 0..27
    const int bb = tid & 7;
    const float4* h4p = (const float4*)(sH1 + bb * H);
    const float4* w4  = (const float4*)(fc1_w + m * H);
    float acc = fc1_b[m];
    #pragma unroll
    for (int q = 0; q < H / 4; ++q) {
      const float4 wv = w4[q], hv = h4p[q];
      FMA4(acc, wv, hv);
    }
    lds[OFF_Y + bb * 28 + m] = fmaxf(acc, 0.0f);
  }
  __syncthreads();
  if (tid < BG) {
    float acc = fc2_b[0];
    #pragma unroll
    for (int m = 0; m < 28; ++m)
      acc = fmaf(fc2_w[m], lds[OFF_Y + tid * 28 + m], acc);
    out[blockIdx.x * BG + tid] = acc;
  }
}

extern "C" void kernel_launch(void* const* d_in, const int* in_sizes, int n_in,
                              void* d_out, int out_size, void* d_ws, size_t ws_size,
                              hipStream_t stream)
{
  const float* x     = (const float*)d_in[0];
  const float* w_ih0 = (const float*)d_in[1];
  const float* w_hh0 = (const float*)d_in[2];
  const float* b_ih0 = (const float*)d_in[3];
  const float* b_hh0 = (const float*)d_in[4];
  const float* w_ih1 = (const float*)d_in[5];
  const float* w_hh1 = (const float*)d_in[6];
  const float* b_ih1 = (const float*)d_in[7];
  const float* b_hh1 = (const float*)d_in[8];
  const float* fc1_w = (const float*)d_in[9];
  const float* fc1_b = (const float*)d_in[10];
  const float* fc2_w = (const float*)d_in[11];
  const float* fc2_b = (const float*)d_in[12];
  float* out = (float*)d_out;

  const size_t SHM_BIG   = (size_t)LDS_BIG_FLOATS * sizeof(float);    // 160384 B
  const size_t SHM_SMALL = (size_t)LDS_SMALL_FLOATS * sizeof(float);  //  60032 B

  int dev = 0;
  (void)hipGetDevice(&dev);
  int shmax = 0;
  (void)hipDeviceGetAttribute(&shmax, hipDeviceAttributeMaxSharedMemoryPerBlock, dev);
  hipError_t attr_rc = hipFuncSetAttribute(
      reinterpret_cast<const void*>(lstm_all<true>),
      hipFuncAttributeMaxDynamicSharedMemorySize, (int)SHM_BIG);
  const bool big = (shmax >= (int)SHM_BIG) || (attr_rc == hipSuccess);

  if (big) {
    lstm_all<true><<<NBLK, NTH, SHM_BIG, stream>>>(
        x, w_ih0, w_hh0, b_ih0, b_hh0, w_ih1, w_hh1, b_ih1, b_hh1,
        fc1_w, fc1_b, fc2_w, fc2_b, out);
  } else {
    lstm_all<false><<<NBLK, NTH, SHM_SMALL, stream>>>(
        x, w_ih0, w_hh0, b_ih0, b_hh0, w_ih1, w_hh1, b_ih1, b_hh1,
        fc1_w, fc1_b, fc2_w, fc2_b, out);
  }
}

// Round 4
// 1870.294 us; speedup vs baseline: 1.1373x; 1.1138x over previous
//
#include <hip/hip_runtime.h>

#define B_TOT 2048
#define T_LEN 512
#define IN0   9
#define H     56
#define NG    224              // 4*H gates
#define BG    8                // batch per block
#define NTH   512              // (j 0..63) x (s 0..1) x (bp 0..3); each thread does b={bp,bp+4}
#define NBLK  (B_TOT / BG)     // 256 blocks

#define WHH_FLOATS (NG * H)    // 12544 floats per 224x56 matrix

// LDS float totals (row-major weights, unchanged layout)
#define LDS_BIG_FLOATS   40096   // 3 matrices + biases + h dbuf + y = 160384 B
#define LDS_SMALL_FLOATS 15008   // 1 matrix + biases + h dbuf + y   =  60032 B

__device__ __forceinline__ float rcp_f(float v)  { return __builtin_amdgcn_rcpf(v); }
__device__ __forceinline__ float sigm_f(float v) { return rcp_f(1.0f + __expf(-v)); }
__device__ __forceinline__ float tanh_f(float v) { return 1.0f - 2.0f * rcp_f(1.0f + __expf(2.0f * v)); }

#define FMA4(acc, wv, vv) \
  acc = fmaf((wv).x, (vv).x, acc); acc = fmaf((wv).y, (vv).y, acc); \
  acc = fmaf((wv).z, (vv).z, acc); acc = fmaf((wv).w, (vv).w, acc)

template<bool BIG>
__global__
__attribute__((amdgpu_flat_work_group_size(NTH, NTH), amdgpu_waves_per_eu(2, 2)))
void lstm_all(const float* __restrict__ x,
              const float* __restrict__ w_ih0, const float* __restrict__ w_hh0,
              const float* __restrict__ b_ih0, const float* __restrict__ b_hh0,
              const float* __restrict__ w_ih1, const float* __restrict__ w_hh1,
              const float* __restrict__ b_ih1, const float* __restrict__ b_hh1,
              const float* __restrict__ fc1_w, const float* __restrict__ fc1_b,
              const float* __restrict__ fc2_w, const float* __restrict__ fc2_b,
              float* __restrict__ out)
{
  extern __shared__ float lds[];
  constexpr int OFF_WIH1 = WHH_FLOATS;                       // BIG only
  constexpr int OFF_WHH1 = 2 * WHH_FLOATS;                   // BIG only
  constexpr int OFF_B0   = BIG ? 3 * WHH_FLOATS : WHH_FLOATS;
  constexpr int OFF_B1   = OFF_B0 + NG;
  constexpr int OFF_H0   = OFF_B1 + NG;                      // [2][BG][H]
  constexpr int OFF_H1   = OFF_H0 + 2 * BG * H;              // [2][BG][H]
  constexpr int OFF_Y    = OFF_H1 + 2 * BG * H;              // [BG][28]

  const int tid = threadIdx.x;

  // ---- stage weights / biases into LDS, zero h state ----
  for (int i = tid; i < WHH_FLOATS / 4; i += NTH)
    ((float4*)(lds))[i] = ((const float4*)w_hh0)[i];
  if (BIG) {
    for (int i = tid; i < WHH_FLOATS / 4; i += NTH)
      ((float4*)(lds + OFF_WIH1))[i] = ((const float4*)w_ih1)[i];
    for (int i = tid; i < WHH_FLOATS / 4; i += NTH)
      ((float4*)(lds + OFF_WHH1))[i] = ((const float4*)w_hh1)[i];
  }
  for (int i = tid; i < NG; i += NTH) {
    lds[OFF_B0 + i] = b_ih0[i] + b_hh0[i];
    lds[OFF_B1 + i] = b_ih1[i] + b_hh1[i];
  }
  for (int i = tid; i < 4 * BG * H; i += NTH)
    lds[OFF_H0 + i] = 0.0f;

  // thread decomposition: 8-lane phases share (j,s) -> weight reads broadcast
  const int j  = tid >> 3;         // hidden unit 0..63 (active < 56)
  const int s  = (tid >> 2) & 1;   // half of the dot products
  const int bp = tid & 3;          // batch pair id: handles b=bp and b=bp+4
  const bool act = (j < H);
  const int jj = act ? j : 0;      // clamped for safe addressing
  const int s7 = s * 7;            // float4 offset into the 14-float4 row

  // x-dot split: s==0 -> k in [0,5), s==1 -> k in [5,9) (5th slot zero-padded)
  float wih[4][5];
  #pragma unroll
  for (int g = 0; g < 4; ++g) {
    #pragma unroll
    for (int kk = 0; kk < 5; ++kk) {
      const int idx = s * 5 + kk;
      const int ci  = (idx > 8) ? 8 : idx;
      const float wv = w_ih0[(g * H + jj) * IN0 + ci];
      wih[g][kk] = (act && idx < 9) ? wv : 0.0f;
    }
  }

  __syncthreads();

  // biases: s==0 half carries them (select, not branch)
  const float ssel = (s == 0) ? 1.0f : 0.0f;
  const float bi0 = lds[OFF_B0 + jj] * ssel;
  const float bf0 = lds[OFF_B0 + H + jj] * ssel;
  const float bg0 = lds[OFF_B0 + 2 * H + jj] * ssel;
  const float bo0 = lds[OFF_B0 + 3 * H + jj] * ssel;
  const float bi1 = lds[OFF_B1 + jj] * ssel;
  const float bf1 = lds[OFF_B1 + H + jj] * ssel;
  const float bg1 = lds[OFF_B1 + 2 * H + jj] * ssel;
  const float bo1 = lds[OFF_B1 + 3 * H + jj] * ssel;

  const float* Wih1 = BIG ? (lds + OFF_WIH1) : w_ih1;
  const float* Whh1 = BIG ? (lds + OFF_WHH1) : w_hh1;

  // per-thread half-row weight pointers (7 float4 each)
  const float4* w0i  = (const float4*)(lds  + (0 * H + jj) * H) + s7;
  const float4* w0f  = (const float4*)(lds  + (1 * H + jj) * H) + s7;
  const float4* w0g  = (const float4*)(lds  + (2 * H + jj) * H) + s7;
  const float4* w0o  = (const float4*)(lds  + (3 * H + jj) * H) + s7;
  const float4* w1ii = (const float4*)(Wih1 + (0 * H + jj) * H) + s7;
  const float4* w1if = (const float4*)(Wih1 + (1 * H + jj) * H) + s7;
  const float4* w1ig = (const float4*)(Wih1 + (2 * H + jj) * H) + s7;
  const float4* w1io = (const float4*)(Wih1 + (3 * H + jj) * H) + s7;
  const float4* w1hi = (const float4*)(Whh1 + (0 * H + jj) * H) + s7;
  const float4* w1hf = (const float4*)(Whh1 + (1 * H + jj) * H) + s7;
  const float4* w1hg = (const float4*)(Whh1 + (2 * H + jj) * H) + s7;
  const float4* w1ho = (const float4*)(Whh1 + (3 * H + jj) * H) + s7;

  float* sH0 = lds + OFF_H0;
  float* sH1 = lds + OFF_H1;

  float c0a = 0.f, c1a = 0.f;   // batch bp
  float c0b = 0.f, c1b = 0.f;   // batch bp+4
  const float* xpa = x + (size_t)(blockIdx.x * BG + bp)     * T_LEN * IN0;
  const float* xpb = x + (size_t)(blockIdx.x * BG + bp + 4) * T_LEN * IN0;

  // clamped x indices for this half (5th slot of s==1 is a dummy, weight=0)
  int cidx[5];
  #pragma unroll
  for (int kk = 0; kk < 5; ++kk) {
    const int idx = s * 5 + kk;
    cidx[kk] = (idx > 8) ? 8 : idx;
  }

  float xha[5], xhb[5];
  #pragma unroll
  for (int kk = 0; kk < 5; ++kk) { xha[kk] = xpa[cidx[kk]]; xhb[kk] = xpb[cidx[kk]]; }

  for (int t = 0; t < T_LEN; ++t) {
    const int rr = t & 1;        // read parity
    const int ww = rr ^ 1;       // write parity
    const bool more = (t + 1 < T_LEN);   // wave-uniform

    float xna[5], xnb[5];
    if (more) {
      #pragma unroll
      for (int kk = 0; kk < 5; ++kk) { xna[kk] = xpa[IN0 + cidx[kk]]; xnb[kk] = xpb[IN0 + cidx[kk]]; }
    }

    // -------- layer 0 (uniform control flow until after the shuffles) ------
    {
      float aia = bi0, afa = bf0, aga = bg0, aoa = bo0;
      float aib = bi0, afb = bf0, agb = bg0, aob = bo0;
      #pragma unroll
      for (int kk = 0; kk < 5; ++kk) {
        const float xa = xha[kk], xb = xhb[kk];
        aia = fmaf(wih[0][kk], xa, aia);  aib = fmaf(wih[0][kk], xb, aib);
        afa = fmaf(wih[1][kk], xa, afa);  afb = fmaf(wih[1][kk], xb, afb);
        aga = fmaf(wih[2][kk], xa, aga);  agb = fmaf(wih[2][kk], xb, agb);
        aoa = fmaf(wih[3][kk], xa, aoa);  aob = fmaf(wih[3][kk], xb, aob);
      }
      const float4* hv4a = (const float4*)(sH0 + (rr * BG + bp)     * H) + s7;
      const float4* hv4b = (const float4*)(sH0 + (rr * BG + bp + 4) * H) + s7;
      #pragma unroll
      for (int q = 0; q < 7; ++q) {
        const float4 ha = hv4a[q];
        const float4 hb = hv4b[q];
        float4 wv;
        wv = w0i[q]; FMA4(aia, wv, ha); FMA4(aib, wv, hb);
        wv = w0f[q]; FMA4(afa, wv, ha); FMA4(afb, wv, hb);
        wv = w0g[q]; FMA4(aga, wv, ha); FMA4(agb, wv, hb);
        wv = w0o[q]; FMA4(aoa, wv, ha); FMA4(aob, wv, hb);
      }
      // combine halves — partner differs in bit 2 (the s bit)
      aia += __shfl_xor(aia, 4);  aib += __shfl_xor(aib, 4);
      afa += __shfl_xor(afa, 4);  afb += __shfl_xor(afb, 4);
      aga += __shfl_xor(aga, 4);  agb += __shfl_xor(agb, 4);
      aoa += __shfl_xor(aoa, 4);  aob += __shfl_xor(aob, 4);
      const float iva = sigm_f(aia), fva = sigm_f(afa), gva = tanh_f(aga), ova = sigm_f(aoa);
      const float ivb = sigm_f(aib), fvb = sigm_f(afb), gvb = tanh_f(agb), ovb = sigm_f(aob);
      c0a = fmaf(fva, c0a, iva * gva);
      c0b = fmaf(fvb, c0b, ivb * gvb);
      const float h0a = ova * tanh_f(c0a);
      const float h0b = ovb * tanh_f(c0b);
      if (act && s == 0) {                         // diverge AFTER shuffles
        sH0[(ww * BG + bp)     * H + j] = h0a;
        sH0[(ww * BG + bp + 4) * H + j] = h0b;
      }
    }
    __syncthreads();   // the single per-timestep barrier

    // -------- layer 1 (input = fresh h0) --------
    {
      float aia = bi1, afa = bf1, aga = bg1, aoa = bo1;
      float aib = bi1, afb = bf1, agb = bg1, aob = bo1;
      const float4* uv4a = (const float4*)(sH0 + (ww * BG + bp)     * H) + s7;
      const float4* uv4b = (const float4*)(sH0 + (ww * BG + bp + 4) * H) + s7;
      const float4* hv4a = (const float4*)(sH1 + (rr * BG + bp)     * H) + s7;
      const float4* hv4b = (const float4*)(sH1 + (rr * BG + bp + 4) * H) + s7;
      #pragma unroll
      for (int q = 0; q < 7; ++q) {
        const float4 ua = uv4a[q];
        const float4 ub = uv4b[q];
        const float4 ha = hv4a[q];
        const float4 hb = hv4b[q];
        float4 wv;
        wv = w1ii[q]; FMA4(aia, wv, ua); FMA4(aib, wv, ub);
        wv = w1hi[q]; FMA4(aia, wv, ha); FMA4(aib, wv, hb);
        wv = w1if[q]; FMA4(afa, wv, ua); FMA4(afb, wv, ub);
        wv = w1hf[q]; FMA4(afa, wv, ha); FMA4(afb, wv, hb);
        wv = w1ig[q]; FMA4(aga, wv, ua); FMA4(agb, wv, ub);
        wv = w1hg[q]; FMA4(aga, wv, ha); FMA4(agb, wv, hb);
        wv = w1io[q]; FMA4(aoa, wv, ua); FMA4(aob, wv, ub);
        wv = w1ho[q]; FMA4(aoa, wv, ha); FMA4(aob, wv, hb);
      }
      aia += __shfl_xor(aia, 4);  aib += __shfl_xor(aib, 4);
      afa += __shfl_xor(afa, 4);  afb += __shfl_xor(afb, 4);
      aga += __shfl_xor(aga, 4);  agb += __shfl_xor(agb, 4);
      aoa += __shfl_xor(aoa, 4);  aob += __shfl_xor(aob, 4);
      const float iva = sigm_f(aia), fva = sigm_f(afa), gva = tanh_f(aga), ova = sigm_f(aoa);
      const float ivb = sigm_f(aib), fvb = sigm_f(afb), gvb = tanh_f(agb), ovb = sigm_f(aob);
      c1a = fmaf(fva, c1a, iva * gva);
      c1b = fmaf(fvb, c1b, ivb * gvb);
      const float h1a = ova * tanh_f(c1a);
      const float h1b = ovb * tanh_f(c1b);
      if (act && s == 0) {
        sH1[(ww * BG + bp)     * H + j] = h1a;
        sH1[(ww * BG + bp + 4) * H + j] = h1b;
      }
    }

    if (more) {
      #pragma unroll
      for (int kk = 0; kk < 5; ++kk) { xha[kk] = xna[kk]; xhb[kk] = xnb[kk]; }
    }
    xpa += IN0;
    xpb += IN0;
  }
  __syncthreads();

  // -------- FC head on h1[:, T-1] (final parity after t=511 is buffer 0) ----
  if (tid < 28 * BG) {
    const int m  = tid >> 3;     // 0..27
    const int bb = tid & 7;
    const float4* h4p = (const float4*)(sH1 + bb * H);
    const float4* w4  = (const float4*)(fc1_w + m * H);
    float acc = fc1_b[m];
    #pragma unroll
    for (int q = 0; q < H / 4; ++q) {
      const float4 wv = w4[q], hv = h4p[q];
      FMA4(acc, wv, hv);
    }
    lds[OFF_Y + bb * 28 + m] = fmaxf(acc, 0.0f);
  }
  __syncthreads();
  if (tid < BG) {
    float acc = fc2_b[0];
    #pragma unroll
    for (int m = 0; m < 28; ++m)
      acc = fmaf(fc2_w[m], lds[OFF_Y + tid * 28 + m], acc);
    out[blockIdx.x * BG + tid] = acc;
  }
}

extern "C" void kernel_launch(void* const* d_in, const int* in_sizes, int n_in,
                              void* d_out, int out_size, void* d_ws, size_t ws_size,
                              hipStream_t stream)
{
  const float* x     = (const float*)d_in[0];
  const float* w_ih0 = (const float*)d_in[1];
  const float* w_hh0 = (const float*)d_in[2];
  const float* b_ih0 = (const float*)d_in[3];
  const float* b_hh0 = (const float*)d_in[4];
  const float* w_ih1 = (const float*)d_in[5];
  const float* w_hh1 = (const float*)d_in[6];
  const float* b_ih1 = (const float*)d_in[7];
  const float* b_hh1 = (const float*)d_in[8];
  const float* fc1_w = (const float*)d_in[9];
  const float* fc1_b = (const float*)d_in[10];
  const float* fc2_w = (const float*)d_in[11];
  const float* fc2_b = (const float*)d_in[12];
  float* out = (float*)d_out;

  const size_t SHM_BIG   = (size_t)LDS_BIG_FLOATS * sizeof(float);    // 160384 B
  const size_t SHM_SMALL = (size_t)LDS_SMALL_FLOATS * sizeof(float);  //  60032 B

  int dev = 0;
  (void)hipGetDevice(&dev);
  int shmax = 0;
  (void)hipDeviceGetAttribute(&shmax, hipDeviceAttributeMaxSharedMemoryPerBlock, dev);
  hipError_t attr_rc = hipFuncSetAttribute(
      reinterpret_cast<const void*>(lstm_all<true>),
      hipFuncAttributeMaxDynamicSharedMemorySize, (int)SHM_BIG);
  const bool big = (shmax >= (int)SHM_BIG) || (attr_rc == hipSuccess);

  if (big) {
    lstm_all<true><<<NBLK, NTH, SHM_BIG, stream>>>(
        x, w_ih0, w_hh0, b_ih0, b_hh0, w_ih1, w_hh1, b_ih1, b_hh1,
        fc1_w, fc1_b, fc2_w, fc2_b, out);
  } else {
    lstm_all<false><<<NBLK, NTH, SHM_SMALL, stream>>>(
        x, w_ih0, w_hh0, b_ih0, b_hh0, w_ih1, w_hh1, b_ih1, b_hh1,
        fc1_w, fc1_b, fc2_w, fc2_b, out);
  }
}

// Round 5
// 873.475 us; speedup vs baseline: 2.4351x; 2.1412x over previous
//
#include <hip/hip_runtime.h>
#include <stdint.h>

#define T_LEN 512
#define IN0   9
#define H     56
#define NG    224              // 4*H gate rows
#define BG    8                // batch per block
#define NTH   448              // 7 waves; wave w owns n-tiles {2w, 2w+1}
#define NBLK  256

#define HROW  72               // shorts per h row (64 k-slots + 8 pad) = 144 B
#define HBUF  (16 * HROW)
#define XROW  40               // shorts per x row (32 k-slots + 8 pad) = 80 B
#define XBUF  (16 * XROW)
#define GSTR  12               // floats per gate row in sG (8 batches + 4 pad)

typedef __attribute__((ext_vector_type(8))) short bfrag;   // 8 bf16 (4 VGPR)
typedef __attribute__((ext_vector_type(4))) float ffrag;   // 4 fp32 acc

#define MFMA(a, b, c) __builtin_amdgcn_mfma_f32_16x16x32_bf16((a), (b), (c), 0, 0, 0)

__device__ __forceinline__ uint32_t bf16hi(float x) {
  // RNE float -> bf16, returned as float bits with low 16 cleared
  uint32_t u = __float_as_uint(x);
  return (u + 0x7FFFu + ((u >> 16) & 1u)) & 0xFFFF0000u;
}
__device__ __forceinline__ void split_bf16(float x, short& hs, short& ls) {
  uint32_t hb = bf16hi(x);
  float lf = x - __uint_as_float(hb);
  uint32_t lb = bf16hi(lf);
  hs = (short)(hb >> 16);
  ls = (short)(lb >> 16);
}

__device__ __forceinline__ float rcp_f(float v)  { return __builtin_amdgcn_rcpf(v); }
__device__ __forceinline__ float sigm_f(float v) { return rcp_f(1.0f + __expf(-v)); }
__device__ __forceinline__ float tanh_f(float v) { return 1.0f - 2.0f * rcp_f(1.0f + __expf(2.0f * v)); }

__global__ __launch_bounds__(NTH, 2)
void lstm_mfma(const float* __restrict__ x,
               const float* __restrict__ w_ih0, const float* __restrict__ w_hh0,
               const float* __restrict__ b_ih0, const float* __restrict__ b_hh0,
               const float* __restrict__ w_ih1, const float* __restrict__ w_hh1,
               const float* __restrict__ b_ih1, const float* __restrict__ b_hh1,
               const float* __restrict__ fc1_w, const float* __restrict__ fc1_b,
               const float* __restrict__ fc2_w, const float* __restrict__ fc2_b,
               float* __restrict__ out)
{
  // h state in A-fragment-friendly layout: [layer][parity][hi/lo][16 rows][HROW]
  __shared__ short sH[2][2][2][HBUF];
  __shared__ short sX[2][XBUF];        // [hi/lo][16 rows][XROW]
  __shared__ float sG[NG * GSTR];      // gates transposed: [n][m(+pad)]
  __shared__ float sF[BG * H];         // final h1 (fp32) for FC head
  __shared__ float sY[BG * 28];

  const int tid  = threadIdx.x;
  const int lane = tid & 63;
  const int wv   = tid >> 6;           // wave 0..6
  const int c16  = lane & 15;
  const int quad = lane >> 4;
  const int n0   = 32 * wv + c16;      // gate-row for tile 0 (B free index)
  const int n1   = n0 + 16;            // gate-row for tile 1

  // activation-phase role: 448 = 56 j * 8 b exactly
  const int aj = tid >> 3;             // hidden unit 0..55
  const int ab = tid & 7;              // batch 0..7

  // ---- zero the h/x staging buffers (covers k-padding and rows b>=8) ----
  {
    int* p = (int*)&sH[0][0][0][0];
    for (int i = tid; i < (2 * 2 * 2 * HBUF) / 2; i += NTH) p[i] = 0;
    int* q = (int*)&sX[0][0];
    for (int i = tid; i < (2 * XBUF) / 2; i += NTH) q[i] = 0;
  }

  // ---- B-fragments (weights, bf16 hi/lo) -> registers, held all kernel ----
  // B layout: lane holds B[n = lane&15 (+tile base)][k = quad*8 + jj]
  bfrag B0h[2][3], B0l[2][3], B1h[2][4], B1l[2][4];
  {
    const float* srcs0[3] = { w_hh0, w_hh0, w_ih0 };
    const int klim0[3]  = { H, H, IN0 };
    const int kbase0[3] = { 0, 32, 0 };
    #pragma unroll
    for (int ts = 0; ts < 2; ++ts) {
      const int n = ts ? n1 : n0;
      #pragma unroll
      for (int s = 0; s < 3; ++s) {
        union { short sh[8]; bfrag v; } uh, ul;
        #pragma unroll
        for (int jj = 0; jj < 8; ++jj) {
          const int k = kbase0[s] + quad * 8 + jj;
          const float w = (k < klim0[s]) ? srcs0[s][n * klim0[s] + k] : 0.0f;
          split_bf16(w, uh.sh[jj], ul.sh[jj]);
        }
        B0h[ts][s] = uh.v; B0l[ts][s] = ul.v;
      }
    }
    const float* srcs1[4] = { w_ih1, w_ih1, w_hh1, w_hh1 };
    const int kbase1[4] = { 0, 32, 0, 32 };
    #pragma unroll
    for (int ts = 0; ts < 2; ++ts) {
      const int n = ts ? n1 : n0;
      #pragma unroll
      for (int s = 0; s < 4; ++s) {
        union { short sh[8]; bfrag v; } uh, ul;
        #pragma unroll
        for (int jj = 0; jj < 8; ++jj) {
          const int k = kbase1[s] + quad * 8 + jj;
          const float w = (k < H) ? srcs1[s][n * H + k] : 0.0f;
          split_bf16(w, uh.sh[jj], ul.sh[jj]);
        }
        B1h[ts][s] = uh.v; B1l[ts][s] = ul.v;
      }
    }
  }

  // biases folded into accumulator init (C cols = n, same value for all rows)
  const float bias00 = b_ih0[n0] + b_hh0[n0];
  const float bias01 = b_ih0[n1] + b_hh0[n1];
  const float bias10 = b_ih1[n0] + b_hh1[n0];
  const float bias11 = b_ih1[n1] + b_hh1[n1];

  const float* xrow = x + (size_t)(blockIdx.x * BG + ab) * T_LEN * IN0;

  __syncthreads();                       // zero-fill visible
  if (aj < IN0) {                        // stage x(t=0) in A layout
    short hs, ls; split_bf16(xrow[aj], hs, ls);
    sX[0][ab * XROW + aj] = hs;
    sX[1][ab * XROW + aj] = ls;
  }
  __syncthreads();

  float c0 = 0.f, c1 = 0.f;

  for (int t = 0; t < T_LEN; ++t) {
    const int rr = t & 1, ww = rr ^ 1;

    // ---- Phase A: layer-0 gates via MFMA ----
    {
      ffrag a0 = { bias00, bias00, bias00, bias00 };
      ffrag a1 = { bias01, bias01, bias01, bias01 };
      const short* hh = sH[0][rr][0];
      const short* hl = sH[0][rr][1];
      #pragma unroll
      for (int s = 0; s < 2; ++s) {      // recurrent h0, k = s*32 ..
        const int off = c16 * HROW + s * 32 + quad * 8;
        bfrag ah = *(const bfrag*)(hh + off);
        bfrag al = *(const bfrag*)(hl + off);
        a0 = MFMA(ah, B0h[0][s], a0);
        a1 = MFMA(ah, B0h[1][s], a1);
        a0 = MFMA(ah, B0l[0][s], a0);
        a1 = MFMA(ah, B0l[1][s], a1);
        a0 = MFMA(al, B0h[0][s], a0);
        a1 = MFMA(al, B0h[1][s], a1);
      }
      {                                  // x contribution, K=9 padded to 32
        const int off = c16 * XROW + quad * 8;
        bfrag ah = *(const bfrag*)(sX[0] + off);
        bfrag al = *(const bfrag*)(sX[1] + off);
        a0 = MFMA(ah, B0h[0][2], a0);
        a1 = MFMA(ah, B0h[1][2], a1);
        a0 = MFMA(ah, B0l[0][2], a0);
        a1 = MFMA(ah, B0l[1][2], a1);
        a0 = MFMA(al, B0h[0][2], a0);
        a1 = MFMA(al, B0h[1][2], a1);
      }
      if (quad < 2) {                    // D rows m = quad*4+reg; valid m<8
        *(ffrag*)(sG + n0 * GSTR + quad * 4) = a0;
        *(ffrag*)(sG + n1 * GSTR + quad * 4) = a1;
      }
    }
    __syncthreads();

    // ---- Phase B: layer-0 activations ----
    {
      const float gi = sG[(0 * H + aj) * GSTR + ab];
      const float gf = sG[(1 * H + aj) * GSTR + ab];
      const float gg = sG[(2 * H + aj) * GSTR + ab];
      const float go = sG[(3 * H + aj) * GSTR + ab];
      const float iv = sigm_f(gi), fv = sigm_f(gf), gv = tanh_f(gg), ov = sigm_f(go);
      c0 = fmaf(fv, c0, iv * gv);
      const float h0 = ov * tanh_f(c0);
      short hs, ls; split_bf16(h0, hs, ls);
      sH[0][ww][0][ab * HROW + aj] = hs;
      sH[0][ww][1][ab * HROW + aj] = ls;
    }
    __syncthreads();

    // ---- Phase C: layer-1 gates via MFMA (u = fresh h0, h = h1 prev) ----
    {
      ffrag a0 = { bias10, bias10, bias10, bias10 };
      ffrag a1 = { bias11, bias11, bias11, bias11 };
      const short* uh = sH[0][ww][0];
      const short* ul_ = sH[0][ww][1];
      const short* hh = sH[1][rr][0];
      const short* hl = sH[1][rr][1];
      #pragma unroll
      for (int s = 0; s < 4; ++s) {
        const short* ph = (s < 2) ? uh : hh;
        const short* pl = (s < 2) ? ul_ : hl;
        const int off = c16 * HROW + (s & 1) * 32 + quad * 8;
        bfrag ah = *(const bfrag*)(ph + off);
        bfrag al = *(const bfrag*)(pl + off);
        a0 = MFMA(ah, B1h[0][s], a0);
        a1 = MFMA(ah, B1h[1][s], a1);
        a0 = MFMA(ah, B1l[0][s], a0);
        a1 = MFMA(ah, B1l[1][s], a1);
        a0 = MFMA(al, B1h[0][s], a0);
        a1 = MFMA(al, B1h[1][s], a1);
      }
      if (quad < 2) {
        *(ffrag*)(sG + n0 * GSTR + quad * 4) = a0;
        *(ffrag*)(sG + n1 * GSTR + quad * 4) = a1;
      }
    }
    __syncthreads();

    // ---- Phase D: layer-1 activations + x(t+1) staging + final capture ----
    {
      const float gi = sG[(0 * H + aj) * GSTR + ab];
      const float gf = sG[(1 * H + aj) * GSTR + ab];
      const float gg = sG[(2 * H + aj) * GSTR + ab];
      const float go = sG[(3 * H + aj) * GSTR + ab];
      const float iv = sigm_f(gi), fv = sigm_f(gf), gv = tanh_f(gg), ov = sigm_f(go);
      c1 = fmaf(fv, c1, iv * gv);
      const float h1 = ov * tanh_f(c1);
      short hs, ls; split_bf16(h1, hs, ls);
      sH[1][ww][0][ab * HROW + aj] = hs;
      sH[1][ww][1][ab * HROW + aj] = ls;
      if (t == T_LEN - 1) sF[ab * H + aj] = h1;
    }
    if (aj < IN0) {                      // stage x for next timestep
      const int tn = (t + 1 < T_LEN) ? (t + 1) : (T_LEN - 1);
      short hs, ls; split_bf16(xrow[tn * IN0 + aj], hs, ls);
      sX[0][ab * XROW + aj] = hs;
      sX[1][ab * XROW + aj] = ls;
    }
    __syncthreads();
  }

  // ---- FC head on final h1 (fp32, from sF) ----
  if (tid < 28 * BG) {
    const int m  = tid >> 3;             // 0..27
    const int bb = tid & 7;
    float acc = fc1_b[m];
    const float4* w4 = (const float4*)(fc1_w + m * H);
    const float4* h4 = (const float4*)(sF + bb * H);
    #pragma unroll
    for (int qq = 0; qq < H / 4; ++qq) {
      const float4 wv4 = w4[qq], hv4 = h4[qq];
      acc = fmaf(wv4.x, hv4.x, acc);
      acc = fmaf(wv4.y, hv4.y, acc);
      acc = fmaf(wv4.z, hv4.z, acc);
      acc = fmaf(wv4.w, hv4.w, acc);
    }
    sY[bb * 28 + m] = fmaxf(acc, 0.0f);
  }
  __syncthreads();
  if (tid < BG) {
    float acc = fc2_b[0];
    #pragma unroll
    for (int m = 0; m < 28; ++m)
      acc = fmaf(fc2_w[m], sY[tid * 28 + m], acc);
    out[blockIdx.x * BG + tid] = acc;
  }
}

extern "C" void kernel_launch(void* const* d_in, const int* in_sizes, int n_in,
                              void* d_out, int out_size, void* d_ws, size_t ws_size,
                              hipStream_t stream)
{
  const float* x     = (const float*)d_in[0];
  const float* w_ih0 = (const float*)d_in[1];
  const float* w_hh0 = (const float*)d_in[2];
  const float* b_ih0 = (const float*)d_in[3];
  const float* b_hh0 = (const float*)d_in[4];
  const float* w_ih1 = (const float*)d_in[5];
  const float* w_hh1 = (const float*)d_in[6];
  const float* b_ih1 = (const float*)d_in[7];
  const float* b_hh1 = (const float*)d_in[8];
  const float* fc1_w = (const float*)d_in[9];
  const float* fc1_b = (const float*)d_in[10];
  const float* fc2_w = (const float*)d_in[11];
  const float* fc2_b = (const float*)d_in[12];
  float* out = (float*)d_out;

  lstm_mfma<<<NBLK, NTH, 0, stream>>>(
      x, w_ih0, w_hh0, b_ih0, b_hh0, w_ih1, w_hh1, b_ih1, b_hh1,
      fc1_w, fc1_b, fc2_w, fc2_b, out);
}

// Round 6
// 730.195 us; speedup vs baseline: 2.9130x; 1.1962x over previous
//
#include <hip/hip_runtime.h>
#include <stdint.h>

#define T_LEN 512
#define IN0   9
#define H     56
#define BG    8
#define NTH   448              // 7 waves; wave w owns n' in [32w, 32w+32)
#define NBLK  256
#define NW    7

#define ATILE 512              // shorts per 16x32 A-tile (1024 B, frag-linear)
#define ABUF  1024             // shorts per (layer,parity,part): 2 k-step tiles
#define SROW  36               // floats per scratch row (32 + 4 pad)

typedef __attribute__((ext_vector_type(8))) short bfrag;   // 8 bf16
typedef __attribute__((ext_vector_type(4))) float ffrag;   // 4 fp32

#define MFMA(a, b, c) __builtin_amdgcn_mfma_f32_16x16x32_bf16((a), (b), (c), 0, 0, 0)

__device__ __forceinline__ uint32_t bf16hi(float x) {
  uint32_t u = __float_as_uint(x);
  return (u + 0x7FFFu + ((u >> 16) & 1u)) & 0xFFFF0000u;
}
__device__ __forceinline__ void split_bf16(float x, short& hs, short& ls) {
  uint32_t hb = bf16hi(x);
  float lf = x - __uint_as_float(hb);
  uint32_t lb = bf16hi(lf);
  hs = (short)(hb >> 16);
  ls = (short)(lb >> 16);
}

__device__ __forceinline__ float rcp_f(float v)  { return __builtin_amdgcn_rcpf(v); }
__device__ __forceinline__ float sigm_f(float v) { return rcp_f(1.0f + __expf(-v)); }
__device__ __forceinline__ float tanh_f(float v) { return 1.0f - 2.0f * rcp_f(1.0f + __expf(2.0f * v)); }

__global__ __launch_bounds__(NTH, 2)
void lstm_mfma2(const float* __restrict__ x,
                const float* __restrict__ w_ih0, const float* __restrict__ w_hh0,
                const float* __restrict__ b_ih0, const float* __restrict__ b_hh0,
                const float* __restrict__ w_ih1, const float* __restrict__ w_hh1,
                const float* __restrict__ b_ih1, const float* __restrict__ b_hh1,
                const float* __restrict__ fc1_w, const float* __restrict__ fc1_b,
                const float* __restrict__ fc2_w, const float* __restrict__ fc2_b,
                float* __restrict__ out)
{
  // h state, fragment-linear: lane L's A-frag for k-step s at [s*ATILE + 8*L]
  __shared__ short sA[2][2][2][ABUF];   // [layer][parity][hi/lo]
  __shared__ float sS[2][NW][16][SROW]; // per-phase, per-wave gate scratch
  __shared__ float sF[BG * H];
  __shared__ float sY[BG * 28];

  const int tid  = threadIdx.x;
  const int lane = tid & 63;
  const int w    = tid >> 6;           // wave 0..6
  const int c16  = lane & 15;
  const int quad = lane >> 4;

  // activation identity: lane = b*8 + jl  (8-lane groups share b -> contiguous b128 scratch reads)
  const int b  = lane >> 3;            // batch 0..7
  const int jl = lane & 7;             // local hidden 0..7
  const int aj = 8 * w + jl;           // global hidden 0..55

  // ---- zero A-frag buffers (covers m>=8 rows and k>=56 padding) ----
  for (int i = tid; i < (2 * 2 * 2 * ABUF) / 2; i += NTH) ((int*)sA)[i] = 0;

  // ---- B-fragments (gate-interleaved n' = 4j+g), bf16 hi/lo, in registers ----
  bfrag B0h[2][2], B0l[2][2];          // [tile][kstep]   layer0 Whh
  bfrag B1h[2][2][2], B1l[2][2][2];    // [op:0=Wih1,1=Whh1][tile][kstep]
  #pragma unroll
  for (int ts = 0; ts < 2; ++ts) {
    const int np = 32 * w + 16 * ts + c16;
    const int jb = np >> 2, gb = np & 3;
    const int row = gb * H + jb;
    #pragma unroll
    for (int s = 0; s < 2; ++s) {
      union { short sh[8]; bfrag v; } u0h, u0l, uih, uil, uhh, uhl;
      #pragma unroll
      for (int jj = 0; jj < 8; ++jj) {
        const int k = s * 32 + quad * 8 + jj;
        const bool ok = (k < H);
        float w0 = ok ? w_hh0[row * H + k] : 0.0f;
        float wi = ok ? w_ih1[row * H + k] : 0.0f;
        float wh = ok ? w_hh1[row * H + k] : 0.0f;
        split_bf16(w0, u0h.sh[jj], u0l.sh[jj]);
        split_bf16(wi, uih.sh[jj], uil.sh[jj]);
        split_bf16(wh, uhh.sh[jj], uhl.sh[jj]);
      }
      B0h[ts][s] = u0h.v;    B0l[ts][s] = u0l.v;
      B1h[0][ts][s] = uih.v; B1l[0][ts][s] = uil.v;
      B1h[1][ts][s] = uhh.v; B1l[1][ts][s] = uhl.v;
    }
  }

  // per-lane (b, aj) constants
  float wx[4][IN0], bs0[4], bs1[4];
  #pragma unroll
  for (int g = 0; g < 4; ++g) {
    bs0[g] = b_ih0[g * H + aj] + b_hh0[g * H + aj];
    bs1[g] = b_ih1[g * H + aj] + b_hh1[g * H + aj];
    #pragma unroll
    for (int k = 0; k < IN0; ++k)
      wx[g][k] = w_ih0[(g * H + aj) * IN0 + k];
  }

  // h-write offset (shorts) for element (b, aj), constant per lane
  const int s_  = aj >> 5;
  const int k_  = aj & 31;
  const int ohw = s_ * ATILE + (k_ >> 3) * 128 + b * 8 + (k_ & 7);

  const float* xrow = x + (size_t)(blockIdx.x * BG + b) * T_LEN * IN0;
  float xcur[IN0], xnxt[IN0];
  #pragma unroll
  for (int k = 0; k < IN0; ++k) xcur[k] = xrow[k];

  float c0 = 0.f, c1 = 0.f;

  __syncthreads();   // zero-fill of sA visible

  for (int t = 0; t < T_LEN; ++t) {
    const int rr = t & 1, ww = rr ^ 1;

    // prefetch x(t+1)
    const int tn = (t + 1 < T_LEN) ? (t + 1) : t;
    #pragma unroll
    for (int k = 0; k < IN0; ++k) xnxt[k] = xrow[tn * IN0 + k];

    // ---- Phase A: layer-0 gates (12 MFMAs) + exact fp32 x-path ----
    {
      bfrag Ah[2], Al[2], Hh[2], Hl[2];
      #pragma unroll
      for (int s = 0; s < 2; ++s) {
        Ah[s] = *(const bfrag*)(sA[0][rr][0] + s * ATILE + lane * 8);
        Al[s] = *(const bfrag*)(sA[0][rr][1] + s * ATILE + lane * 8);
        Hh[s] = *(const bfrag*)(sA[1][rr][0] + s * ATILE + lane * 8);  // prefetch for Phase C
        Hl[s] = *(const bfrag*)(sA[1][rr][1] + s * ATILE + lane * 8);
      }
      ffrag acc[2] = { {0.f,0.f,0.f,0.f}, {0.f,0.f,0.f,0.f} };
      #pragma unroll
      for (int s = 0; s < 2; ++s)
        #pragma unroll
        for (int ts = 0; ts < 2; ++ts) {
          acc[ts] = MFMA(Ah[s], B0h[ts][s], acc[ts]);
          acc[ts] = MFMA(Ah[s], B0l[ts][s], acc[ts]);
          acc[ts] = MFMA(Al[s], B0h[ts][s], acc[ts]);
        }

      float xd[4] = {0.f, 0.f, 0.f, 0.f};
      #pragma unroll
      for (int k = 0; k < IN0; ++k) {
        const float xv = xcur[k];
        xd[0] = fmaf(wx[0][k], xv, xd[0]);
        xd[1] = fmaf(wx[1][k], xv, xd[1]);
        xd[2] = fmaf(wx[2][k], xv, xd[2]);
        xd[3] = fmaf(wx[3][k], xv, xd[3]);
      }

      #pragma unroll
      for (int r = 0; r < 4; ++r) {
        sS[0][w][quad * 4 + r][c16]      = acc[0][r];
        sS[0][w][quad * 4 + r][16 + c16] = acc[1][r];
      }
      const float4 g4 = *(const float4*)&sS[0][w][b][4 * jl];  // same-wave, lgkmcnt-ordered
      const float gi = g4.x + bs0[0] + xd[0];
      const float gf = g4.y + bs0[1] + xd[1];
      const float gg = g4.z + bs0[2] + xd[2];
      const float go = g4.w + bs0[3] + xd[3];
      const float iv = sigm_f(gi), fv = sigm_f(gf), gv = tanh_f(gg), ov = sigm_f(go);
      c0 = fmaf(fv, c0, iv * gv);
      const float h0v = ov * tanh_f(c0);
      short hs, ls; split_bf16(h0v, hs, ls);
      sA[0][ww][0][ohw] = hs;
      sA[0][ww][1][ohw] = ls;

      __syncthreads();   // barrier 1: fresh h0[ww] visible

      // ---- Phase C: layer-1 gates (24 MFMAs) ----
      bfrag Uh[2], Ul[2];
      #pragma unroll
      for (int s = 0; s < 2; ++s) {
        Uh[s] = *(const bfrag*)(sA[0][ww][0] + s * ATILE + lane * 8);
        Ul[s] = *(const bfrag*)(sA[0][ww][1] + s * ATILE + lane * 8);
      }
      ffrag bcc[2] = { {0.f,0.f,0.f,0.f}, {0.f,0.f,0.f,0.f} };
      #pragma unroll
      for (int s = 0; s < 2; ++s)
        #pragma unroll
        for (int ts = 0; ts < 2; ++ts) {
          bcc[ts] = MFMA(Hh[s], B1h[1][ts][s], bcc[ts]);   // h1 part (preloaded)
          bcc[ts] = MFMA(Hh[s], B1l[1][ts][s], bcc[ts]);
          bcc[ts] = MFMA(Hl[s], B1h[1][ts][s], bcc[ts]);
        }
      #pragma unroll
      for (int s = 0; s < 2; ++s)
        #pragma unroll
        for (int ts = 0; ts < 2; ++ts) {
          bcc[ts] = MFMA(Uh[s], B1h[0][ts][s], bcc[ts]);   // u = fresh h0
          bcc[ts] = MFMA(Uh[s], B1l[0][ts][s], bcc[ts]);
          bcc[ts] = MFMA(Ul[s], B1h[0][ts][s], bcc[ts]);
        }

      #pragma unroll
      for (int r = 0; r < 4; ++r) {
        sS[1][w][quad * 4 + r][c16]      = bcc[0][r];
        sS[1][w][quad * 4 + r][16 + c16] = bcc[1][r];
      }
      const float4 q4 = *(const float4*)&sS[1][w][b][4 * jl];
      const float qi = q4.x + bs1[0];
      const float qf = q4.y + bs1[1];
      const float qg = q4.z + bs1[2];
      const float qo = q4.w + bs1[3];
      const float iw = sigm_f(qi), fw = sigm_f(qf), gw = tanh_f(qg), ow = sigm_f(qo);
      c1 = fmaf(fw, c1, iw * gw);
      const float h1v = ow * tanh_f(c1);
      short h1s, h1l; split_bf16(h1v, h1s, h1l);
      sA[1][ww][0][ohw] = h1s;
      sA[1][ww][1][ohw] = h1l;
      if (t == T_LEN - 1) sF[b * H + aj] = h1v;
    }

    #pragma unroll
    for (int k = 0; k < IN0; ++k) xcur[k] = xnxt[k];

    __syncthreads();   // barrier 2: fresh h1[ww] (and h0 reuse) ordered
  }

  // ---- FC head ----
  if (tid < 28 * BG) {
    const int m  = tid >> 3;
    const int bb = tid & 7;
    float acc = fc1_b[m];
    const float4* w4 = (const float4*)(fc1_w + m * H);
    const float4* h4 = (const float4*)(sF + bb * H);
    #pragma unroll
    for (int qq = 0; qq < H / 4; ++qq) {
      const float4 wv4 = w4[qq], hv4 = h4[qq];
      acc = fmaf(wv4.x, hv4.x, acc);
      acc = fmaf(wv4.y, hv4.y, acc);
      acc = fmaf(wv4.z, hv4.z, acc);
      acc = fmaf(wv4.w, hv4.w, acc);
    }
    sY[bb * 28 + m] = fmaxf(acc, 0.0f);
  }
  __syncthreads();
  if (tid < BG) {
    float acc = fc2_b[0];
    #pragma unroll
    for (int m = 0; m < 28; ++m)
      acc = fmaf(fc2_w[m], sY[tid * 28 + m], acc);
    out[blockIdx.x * BG + tid] = acc;
  }
}

extern "C" void kernel_launch(void* const* d_in, const int* in_sizes, int n_in,
                              void* d_out, int out_size, void* d_ws, size_t ws_size,
                              hipStream_t stream)
{
  const float* x     = (const float*)d_in[0];
  const float* w_ih0 = (const float*)d_in[1];
  const float* w_hh0 = (const float*)d_in[2];
  const float* b_ih0 = (const float*)d_in[3];
  const float* b_hh0 = (const float*)d_in[4];
  const float* w_ih1 = (const float*)d_in[5];
  const float* w_hh1 = (const float*)d_in[6];
  const float* b_ih1 = (const float*)d_in[7];
  const float* b_hh1 = (const float*)d_in[8];
  const float* fc1_w = (const float*)d_in[9];
  const float* fc1_b = (const float*)d_in[10];
  const float* fc2_w = (const float*)d_in[11];
  const float* fc2_b = (const float*)d_in[12];
  float* out = (float*)d_out;

  lstm_mfma2<<<NBLK, NTH, 0, stream>>>(
      x, w_ih0, w_hh0, b_ih0, b_hh0, w_ih1, w_hh1, b_ih1, b_hh1,
      fc1_w, fc1_b, fc2_w, fc2_b, out);
}

// Round 7
// 706.741 us; speedup vs baseline: 3.0096x; 1.0332x over previous
//
#include <hip/hip_runtime.h>
#include <stdint.h>

#define T_LEN 512
#define IN0   9
#define H     56
#define BG    8
#define NW    14
#define NTH   (NW * 64)        // 896 threads, 14 waves; wave w owns n' in [16w,16w+16)
#define NBLK  256
#define SROW  20               // scratch row stride in floats (16 + 4 pad)

typedef __attribute__((ext_vector_type(8))) short bfrag;   // 8 bf16
typedef __attribute__((ext_vector_type(4))) float ffrag;   // 4 fp32

#define MFMA(a,b,c) __builtin_amdgcn_mfma_f32_16x16x32_bf16((a),(b),(c),0,0,0)

__device__ __forceinline__ uint32_t bf16hi(float x) {
  uint32_t u = __float_as_uint(x);
  return (u + 0x7FFFu + ((u >> 16) & 1u)) & 0xFFFF0000u;
}
__device__ __forceinline__ void split_bf16(float x, short& hs, short& ls) {
  uint32_t hb = bf16hi(x);
  float lf = x - __uint_as_float(hb);
  hs = (short)(hb >> 16);
  ls = (short)(bf16hi(lf) >> 16);
}
__device__ __forceinline__ float rcp_f(float v)  { return __builtin_amdgcn_rcpf(v); }
__device__ __forceinline__ float sigm_f(float v) { return rcp_f(1.0f + __expf(-v)); }
__device__ __forceinline__ float tanh_f(float v) { return 1.0f - 2.0f * rcp_f(1.0f + __expf(2.0f * v)); }

__global__ __launch_bounds__(NTH, 4)
void lstm_mfma3(const float* __restrict__ x,
                const float* __restrict__ w_ih0, const float* __restrict__ w_hh0,
                const float* __restrict__ b_ih0, const float* __restrict__ b_hh0,
                const float* __restrict__ w_ih1, const float* __restrict__ w_hh1,
                const float* __restrict__ b_ih1, const float* __restrict__ b_hh1,
                const float* __restrict__ fc1_w, const float* __restrict__ fc1_b,
                const float* __restrict__ fc2_w, const float* __restrict__ fc2_b,
                float* __restrict__ out)
{
  // A-state per (layer, parity): 16 rows x 64 k-slots, fragment-linear.
  // rows 0-7 = hi(value for batch b), rows 8-15 = lo residual.
  // layer-0 k 0..55 = h0, k 56..63 = x[0..7]. layer-1 k 56..63 stay zero.
  __shared__ __align__(16) short sA[2][2][1024];
  __shared__ __align__(16) float sS[2][NW][16][SROW];  // wave-private gate scratch
  __shared__ float sF[BG * H];
  __shared__ float sY[BG * 28];

  const int tid  = threadIdx.x;
  const int lane = tid & 63;
  const int w    = tid >> 6;          // wave 0..13
  const int c16  = lane & 15;
  const int quad = lane >> 4;

  // n' = 4*j + g gate interleave; wave w covers j in [4w, 4w+4), all 4 gates
  const int np   = 16 * w + c16;
  const int jb   = np >> 2, gb = np & 3;
  const int wrow = gb * H + jb;       // row in PyTorch [4H, K] weight

  for (int i = tid; i < (int)(sizeof(sA) / 4); i += NTH) ((int*)sA)[i] = 0;

  // ---- B-fragments (bf16 hi/lo) in registers: B[n=c16][k=quad*8+jj] ----
  bfrag B0h[2], B0l[2], Buh[2], Bul[2], Bhh[2], Bhl[2];
  #pragma unroll
  for (int s = 0; s < 2; ++s) {
    union { short sh[8]; bfrag v; } a0h, a0l, auh, aul, ahh, ahl;
    #pragma unroll
    for (int jj = 0; jj < 8; ++jj) {
      const int k = 32 * s + quad * 8 + jj;
      const float w0 = (k < H) ? w_hh0[wrow * H + k] : w_ih0[wrow * IN0 + (k - 56)];
      const float wu = (k < H) ? w_ih1[wrow * H + k] : 0.0f;
      const float wh = (k < H) ? w_hh1[wrow * H + k] : 0.0f;
      split_bf16(w0, a0h.sh[jj], a0l.sh[jj]);
      split_bf16(wu, auh.sh[jj], aul.sh[jj]);
      split_bf16(wh, ahh.sh[jj], ahl.sh[jj]);
    }
    B0h[s] = a0h.v; B0l[s] = a0l.v;
    Buh[s] = auh.v; Bul[s] = aul.v;
    Bhh[s] = ahh.v; Bhl[s] = ahl.v;
  }

  // activation identity: lanes jl<4 own element (b, aj = 4w+jl)
  const int b    = lane >> 3;
  const int jl   = lane & 7;
  const int jlc  = jl & 3;
  const int aj   = 4 * w + jlc;
  const bool actv = (jl < 4);

  float bs0[4], bs1[4], wx8[4];
  #pragma unroll
  for (int g = 0; g < 4; ++g) {
    bs0[g] = b_ih0[g * H + aj] + b_hh0[g * H + aj];
    bs1[g] = b_ih1[g * H + aj] + b_hh1[g * H + aj];
    wx8[g] = w_ih0[(g * H + aj) * IN0 + 8];
  }

  const int kk   = aj & 31;
  const int offh = (aj >> 5) * 512 + ((kk >> 3) * 16 + b) * 8 + (kk & 7);  // hi; +64 = lo
  const int offx = 512 + (48 + b) * 8 + 2 * jlc;                            // x slots k=56..63

  const float* xrow = x + (size_t)(blockIdx.x * BG + b) * T_LEN * IN0;

  float c0 = 0.f, c1 = 0.f;

  __syncthreads();                    // sA zeros visible

  // stage x(0) into sA[0][0] (all waves redundant, same-value: benign)
  if (actv) {
    float xa = xrow[2 * jlc], xb = xrow[2 * jlc + 1];
    short ah, al, bh, bl;
    split_bf16(xa, ah, al); split_bf16(xb, bh, bl);
    *(uint32_t*)&sA[0][0][offx]      = (uint16_t)ah | ((uint32_t)(uint16_t)bh << 16);
    *(uint32_t*)&sA[0][0][offx + 64] = (uint16_t)al | ((uint32_t)(uint16_t)bl << 16);
  }
  __syncthreads();

  // ---- prologue: L0 gates(0) + act0(0) ----
  {
    const short* pa = sA[0][0];
    bfrag A0 = *(const bfrag*)(pa + lane * 8);
    bfrag A1 = *(const bfrag*)(pa + 512 + lane * 8);
    ffrag acc = {0.f, 0.f, 0.f, 0.f};
    acc = MFMA(A0, B0h[0], acc);
    acc = MFMA(A0, B0l[0], acc);
    acc = MFMA(A1, B0h[1], acc);
    acc = MFMA(A1, B0l[1], acc);
    float* sd = &sS[1][w][0][0];
    #pragma unroll
    for (int r = 0; r < 4; ++r) sd[(quad * 4 + r) * SROW + c16] = acc[r];
    if (actv) {
      const float4 ghi = *(const float4*)&sd[b * SROW + 4 * jlc];
      const float4 glo = *(const float4*)&sd[(b + 8) * SROW + 4 * jlc];
      const float x8 = xrow[8];
      const float gi = ghi.x + glo.x + bs0[0] + wx8[0] * x8;
      const float gf = ghi.y + glo.y + bs0[1] + wx8[1] * x8;
      const float gg = ghi.z + glo.z + bs0[2] + wx8[2] * x8;
      const float go = ghi.w + glo.w + bs0[3] + wx8[3] * x8;
      const float iv = sigm_f(gi), fv = sigm_f(gf), gv = tanh_f(gg), ov = sigm_f(go);
      c0 = fmaf(fv, c0, iv * gv);
      const float h0v = ov * tanh_f(c0);
      short hs, hl; split_bf16(h0v, hs, hl);
      sA[0][1][offh]      = hs;
      sA[0][1][offh + 64] = hl;
      float xa = xrow[IN0 + 2 * jlc], xb = xrow[IN0 + 2 * jlc + 1];
      short ah, al2, bh, bl2;
      split_bf16(xa, ah, al2); split_bf16(xb, bh, bl2);
      *(uint32_t*)&sA[0][1][offx]      = (uint16_t)ah  | ((uint32_t)(uint16_t)bh  << 16);
      *(uint32_t*)&sA[0][1][offx + 64] = (uint16_t)al2 | ((uint32_t)(uint16_t)bl2 << 16);
    }
  }
  __syncthreads();

  // ---- main loop: ONE barrier per timestep ----
  // region t: L1-gates(t) + act1(t) + L0-gates(t+1) + act0(t+1)
  for (int t = 0; t < T_LEN; ++t) {
    const int rr = t & 1, ww = rr ^ 1;
    const bool more = (t + 1 < T_LEN);
    const short* pu = sA[0][ww];      // h0(t) + x(t+1)  — feeds L1(t) AND L0(t+1)
    const short* ph = sA[1][rr];      // h1(t-1)
    bfrag U0 = *(const bfrag*)(pu + lane * 8);
    bfrag U1 = *(const bfrag*)(pu + 512 + lane * 8);
    bfrag H0 = *(const bfrag*)(ph + lane * 8);
    bfrag H1 = *(const bfrag*)(ph + 512 + lane * 8);

    ffrag aU = {0.f, 0.f, 0.f, 0.f}, aH = {0.f, 0.f, 0.f, 0.f};
    aU = MFMA(U0, Buh[0], aU);
    aU = MFMA(U0, Bul[0], aU);
    aU = MFMA(U1, Buh[1], aU);
    aU = MFMA(U1, Bul[1], aU);
    aH = MFMA(H0, Bhh[0], aH);
    aH = MFMA(H0, Bhl[0], aH);
    aH = MFMA(H1, Bhh[1], aH);
    aH = MFMA(H1, Bhl[1], aH);

    ffrag aA = {0.f, 0.f, 0.f, 0.f};
    if (more) {                        // L0(t+1): same U frags, W0 weights
      aA = MFMA(U0, B0h[0], aA);
      aA = MFMA(U0, B0l[0], aA);
      aA = MFMA(U1, B0h[1], aA);
      aA = MFMA(U1, B0l[1], aA);
    }

    float* sc = &sS[0][w][0][0];
    float* sd = &sS[1][w][0][0];
    #pragma unroll
    for (int r = 0; r < 4; ++r) {
      sc[(quad * 4 + r) * SROW + c16] = aU[r] + aH[r];
      sd[(quad * 4 + r) * SROW + c16] = aA[r];
    }

    if (actv) {
      {  // act1(t): h1 update
        const float4 ghi = *(const float4*)&sc[b * SROW + 4 * jlc];
        const float4 glo = *(const float4*)&sc[(b + 8) * SROW + 4 * jlc];
        const float gi = ghi.x + glo.x + bs1[0];
        const float gf = ghi.y + glo.y + bs1[1];
        const float gg = ghi.z + glo.z + bs1[2];
        const float go = ghi.w + glo.w + bs1[3];
        const float iv = sigm_f(gi), fv = sigm_f(gf), gv = tanh_f(gg), ov = sigm_f(go);
        c1 = fmaf(fv, c1, iv * gv);
        const float h1v = ov * tanh_f(c1);
        short hs, hl; split_bf16(h1v, hs, hl);
        sA[1][ww][offh]      = hs;
        sA[1][ww][offh + 64] = hl;
        if (t == T_LEN - 1) sF[b * H + aj] = h1v;
      }
      if (more) {  // act0(t+1): h0 update + x(t+2) staging
        const float4 ghi = *(const float4*)&sd[b * SROW + 4 * jlc];
        const float4 glo = *(const float4*)&sd[(b + 8) * SROW + 4 * jlc];
        const float x8 = xrow[(t + 1) * IN0 + 8];
        const float gi = ghi.x + glo.x + bs0[0] + wx8[0] * x8;
        const float gf = ghi.y + glo.y + bs0[1] + wx8[1] * x8;
        const float gg = ghi.z + glo.z + bs0[2] + wx8[2] * x8;
        const float go = ghi.w + glo.w + bs0[3] + wx8[3] * x8;
        const float iv = sigm_f(gi), fv = sigm_f(gf), gv = tanh_f(gg), ov = sigm_f(go);
        c0 = fmaf(fv, c0, iv * gv);
        const float h0v = ov * tanh_f(c0);
        short hs, hl; split_bf16(h0v, hs, hl);
        sA[0][rr][offh]      = hs;
        sA[0][rr][offh + 64] = hl;
        const int tf = (t + 2 < T_LEN) ? t + 2 : T_LEN - 1;
        float xa = xrow[tf * IN0 + 2 * jlc], xb = xrow[tf * IN0 + 2 * jlc + 1];
        short ah, al2, bh, bl2;
        split_bf16(xa, ah, al2); split_bf16(xb, bh, bl2);
        *(uint32_t*)&sA[0][rr][offx]      = (uint16_t)ah  | ((uint32_t)(uint16_t)bh  << 16);
        *(uint32_t*)&sA[0][rr][offx + 64] = (uint16_t)al2 | ((uint32_t)(uint16_t)bl2 << 16);
      }
    }
    __syncthreads();
  }

  // ---- FC head on final h1 ----
  if (tid < 28 * BG) {
    const int m  = tid >> 3;
    const int bb = tid & 7;
    float acc = fc1_b[m];
    const float4* w4 = (const float4*)(fc1_w + m * H);
    const float4* h4 = (const float4*)(sF + bb * H);
    #pragma unroll
    for (int qq = 0; qq < H / 4; ++qq) {
      const float4 wv4 = w4[qq], hv4 = h4[qq];
      acc = fmaf(wv4.x, hv4.x, acc);
      acc = fmaf(wv4.y, hv4.y, acc);
      acc = fmaf(wv4.z, hv4.z, acc);
      acc = fmaf(wv4.w, hv4.w, acc);
    }
    sY[bb * 28 + m] = fmaxf(acc, 0.0f);
  }
  __syncthreads();
  if (tid < BG) {
    float acc = fc2_b[0];
    #pragma unroll
    for (int m = 0; m < 28; ++m)
      acc = fmaf(fc2_w[m], sY[tid * 28 + m], acc);
    out[blockIdx.x * BG + tid] = acc;
  }
}

extern "C" void kernel_launch(void* const* d_in, const int* in_sizes, int n_in,
                              void* d_out, int out_size, void* d_ws, size_t ws_size,
                              hipStream_t stream)
{
  const float* x     = (const float*)d_in[0];
  const float* w_ih0 = (const float*)d_in[1];
  const float* w_hh0 = (const float*)d_in[2];
  const float* b_ih0 = (const float*)d_in[3];
  const float* b_hh0 = (const float*)d_in[4];
  const float* w_ih1 = (const float*)d_in[5];
  const float* w_hh1 = (const float*)d_in[6];
  const float* b_ih1 = (const float*)d_in[7];
  const float* b_hh1 = (const float*)d_in[8];
  const float* fc1_w = (const float*)d_in[9];
  const float* fc1_b = (const float*)d_in[10];
  const float* fc2_w = (const float*)d_in[11];
  const float* fc2_b = (const float*)d_in[12];
  float* out = (float*)d_out;

  lstm_mfma3<<<NBLK, NTH, 0, stream>>>(
      x, w_ih0, w_hh0, b_ih0, b_hh0, w_ih1, w_hh1, b_ih1, b_hh1,
      fc1_w, fc1_b, fc2_w, fc2_b, out);
}

// Round 8
// 474.108 us; speedup vs baseline: 4.4864x; 1.4907x over previous
//
#include <hip/hip_runtime.h>
#include <stdint.h>

#define T_LEN 512
#define IN0   9
#define H     56
#define BG    8
#define NW    14
#define NTH   (NW * 64)        // 896 threads, 14 waves; wave w owns n' in [16w,16w+16)
#define NBLK  256
#define SROW  20               // scratch row stride in floats (16 + 4 pad)

typedef __attribute__((ext_vector_type(8))) short bfrag;   // 8 bf16
typedef __attribute__((ext_vector_type(4))) float ffrag;   // 4 fp32

#define MFMA(a,b,c) __builtin_amdgcn_mfma_f32_16x16x32_bf16((a),(b),(c),0,0,0)

__device__ __forceinline__ uint32_t bf16hi(float x) {
  uint32_t u = __float_as_uint(x);
  return (u + 0x7FFFu + ((u >> 16) & 1u)) & 0xFFFF0000u;
}
__device__ __forceinline__ void split_bf16(float x, short& hs, short& ls) {
  uint32_t hb = bf16hi(x);
  float lf = x - __uint_as_float(hb);
  hs = (short)(hb >> 16);
  ls = (short)(bf16hi(lf) >> 16);
}
__device__ __forceinline__ float rcp_f(float v)  { return __builtin_amdgcn_rcpf(v); }
__device__ __forceinline__ float sigm_f(float v) { return rcp_f(1.0f + __expf(-v)); }
__device__ __forceinline__ float tanh_f(float v) { return 1.0f - 2.0f * rcp_f(1.0f + __expf(2.0f * v)); }

__global__ __launch_bounds__(NTH, 4)
void lstm_mfma4(const float* __restrict__ x,
                const float* __restrict__ w_ih0, const float* __restrict__ w_hh0,
                const float* __restrict__ b_ih0, const float* __restrict__ b_hh0,
                const float* __restrict__ w_ih1, const float* __restrict__ w_hh1,
                const float* __restrict__ b_ih1, const float* __restrict__ b_hh1,
                const float* __restrict__ fc1_w, const float* __restrict__ fc1_b,
                const float* __restrict__ fc2_w, const float* __restrict__ fc2_b,
                float* __restrict__ out)
{
  // sA[layer*2+parity][1024]: 16 rows x 64 k-slots, fragment-linear.
  // rows 0-7 hi(value), rows 8-15 lo residual. layer0 k 56..63 = x[0..7].
  __shared__ __align__(16) short sA[4][1024];
  __shared__ __align__(16) float sS[2][NW][16][SROW];  // [0]=L1 gates, [1]=L0 gates
  __shared__ float sF[BG * H];
  __shared__ float sY[BG * 28];

  const int tid  = threadIdx.x;
  const int lane = tid & 63;
  const int w    = tid >> 6;
  const int c16  = lane & 15;
  const int quad = lane >> 4;

  const int np   = 16 * w + c16;       // n' = 4j+g
  const int jb   = np >> 2, gb = np & 3;
  const int wrow = gb * H + jb;

  for (int i = tid; i < (int)(sizeof(sA) / 4); i += NTH) ((int*)sA)[i] = 0;

  // ---- B-fragments (bf16 hi/lo) in registers ----
  bfrag B0h[2], B0l[2], Buh[2], Bul[2], Bhh[2], Bhl[2];
  #pragma unroll
  for (int s = 0; s < 2; ++s) {
    union { short sh[8]; bfrag v; } a0h, a0l, auh, aul, ahh, ahl;
    #pragma unroll
    for (int jj = 0; jj < 8; ++jj) {
      const int k = 32 * s + quad * 8 + jj;
      const float w0 = (k < H) ? w_hh0[wrow * H + k] : w_ih0[wrow * IN0 + (k - 56)];
      const float wu = (k < H) ? w_ih1[wrow * H + k] : 0.0f;
      const float wh = (k < H) ? w_hh1[wrow * H + k] : 0.0f;
      split_bf16(w0, a0h.sh[jj], a0l.sh[jj]);
      split_bf16(wu, auh.sh[jj], aul.sh[jj]);
      split_bf16(wh, ahh.sh[jj], ahl.sh[jj]);
    }
    B0h[s] = a0h.v; B0l[s] = a0l.v;
    Buh[s] = auh.v; Bul[s] = aul.v;
    Bhh[s] = ahh.v; Bhl[s] = ahl.v;
  }

  // biases folded into MFMA C-init: only rows 0-7 (quad<2) carry bias
  const float b0v = (quad < 2) ? (b_ih0[wrow] + b_hh0[wrow]) : 0.0f;
  const float b1v = (quad < 2) ? (b_ih1[wrow] + b_hh1[wrow]) : 0.0f;
  const ffrag bias0f = { b0v, b0v, b0v, b0v };
  const ffrag bias1f = { b1v, b1v, b1v, b1v };
  const ffrag zerof  = { 0.f, 0.f, 0.f, 0.f };

  // act identity: half 0 -> act1 (layer1, t); half 1 -> act0 (layer0, t+1)
  const int half = lane >> 5;
  const int bq   = (lane >> 2) & 7;
  const int jlc  = lane & 3;
  const int aj   = 4 * w + jlc;

  float wx8a[4];
  #pragma unroll
  for (int g = 0; g < 4; ++g)
    wx8a[g] = half ? w_ih0[(g * H + aj) * IN0 + 8] : 0.0f;

  // loop-invariant pointers
  const int kk   = aj & 31;
  const int offE = (aj >> 5) * 512 + ((kk >> 3) * 16 + bq) * 8 + (kk & 7);
  short* const hst0 = &sA[0][0] + (half ? 0 : 3 * 1024) + offE;  // RR=0 instance
  short* const hst1 = &sA[0][0] + (half ? 1 * 1024 : 2 * 1024) + offE;  // RR=1
  const int offX = 512 + (48 + bq) * 8 + 2 * jlc;
  short* const xst0 = &sA[0][0] + offX;          // staging into layer0 parity0
  short* const xst1 = &sA[1][0] + offX;          // staging into layer0 parity1
  float* const scW = &sS[0][w][0][0] + quad * 4 * SROW + c16;
  float* const sdW = &sS[1][w][0][0] + quad * 4 * SROW + c16;
  const float* const srd = &sS[half][w][0][0] + bq * SROW + 4 * jlc;
  const short* const sAr = &sA[0][0];

  const size_t xbase = (size_t)(blockIdx.x * BG + bq) * T_LEN * IN0;
  const float* xp8 = x + xbase + 8;              // x8(t) pointer
  const float* xps = x + xbase + IN0 + 2 * jlc;  // staging pointer (x(1) first)

  float cst = 0.f;                               // half0: c1, half1: c0
  __syncthreads();                               // sA zeros visible

  // ---- stage x(0) into buf0 (w0, act0 lanes) ----
  if (w == 0) {
    const float xa = xps[-IN0], xb = xps[1 - IN0];
    if (half) {
      short ah, al2, bh, bl2;
      split_bf16(xa, ah, al2); split_bf16(xb, bh, bl2);
      *(uint32_t*)xst0        = (uint16_t)ah  | ((uint32_t)(uint16_t)bh  << 16);
      *(uint32_t*)(xst0 + 64) = (uint16_t)al2 | ((uint32_t)(uint16_t)bl2 << 16);
    }
  }
  __syncthreads();

  // ---- prologue region: L0(0) + act0(0) -> h0(0), x(1) into buf1 ----
  {
    bfrag A0 = *(const bfrag*)(sAr + lane * 8);
    bfrag A1 = *(const bfrag*)(sAr + 512 + lane * 8);
    ffrag aA = MFMA(A0, B0h[0], bias0f);
    aA = MFMA(A1, B0h[1], aA);
    aA = MFMA(A0, B0l[0], aA);
    aA = MFMA(A1, B0l[1], aA);
    sdW[0] = aA[0]; sdW[SROW] = aA[1]; sdW[2 * SROW] = aA[2]; sdW[3 * SROW] = aA[3];
    const float x8v = xp8[0];
    xp8 += IN0;
    if (half) {
      const float4 ghi = *(const float4*)srd;
      const float4 glo = *(const float4*)(srd + 8 * SROW);
      const float gi = fmaf(wx8a[0], x8v, ghi.x + glo.x);
      const float gf = fmaf(wx8a[1], x8v, ghi.y + glo.y);
      const float gg = fmaf(wx8a[2], x8v, ghi.z + glo.z);
      const float go = fmaf(wx8a[3], x8v, ghi.w + glo.w);
      const float iv = sigm_f(gi), fv = sigm_f(gf), gv = tanh_f(gg), ov = sigm_f(go);
      cst = fmaf(fv, cst, iv * gv);
      const float hv = ov * tanh_f(cst);
      short hs, hl; split_bf16(hv, hs, hl);
      hst1[0] = hs; hst1[64] = hl;
    }
    if (w == 0) {
      const float xa = xps[0], xb = xps[1];
      if (half) {
        short ah, al2, bh, bl2;
        split_bf16(xa, ah, al2); split_bf16(xb, bh, bl2);
        *(uint32_t*)xst1        = (uint16_t)ah  | ((uint32_t)(uint16_t)bh  << 16);
        *(uint32_t*)(xst1 + 64) = (uint16_t)al2 | ((uint32_t)(uint16_t)bl2 << 16);
      }
    }
    xps += IN0;
    __syncthreads();
  }

#define REGION(RR, L0PART, XSTG, LASTR)                                         \
  {                                                                             \
    bfrag U0 = *(const bfrag*)(sAr + (RR ^ 1) * 1024 + lane * 8);               \
    bfrag U1 = *(const bfrag*)(sAr + (RR ^ 1) * 1024 + 512 + lane * 8);         \
    bfrag H0 = *(const bfrag*)(sAr + (2 + RR) * 1024 + lane * 8);               \
    bfrag H1 = *(const bfrag*)(sAr + (2 + RR) * 1024 + 512 + lane * 8);         \
    float x8v = 0.0f;                                                           \
    if (L0PART) { x8v = xp8[0]; xp8 += IN0; }                                   \
    ffrag aU = MFMA(U0, Buh[0], bias1f);                                        \
    aU = MFMA(U1, Buh[1], aU);                                                  \
    aU = MFMA(U0, Bul[0], aU);                                                  \
    aU = MFMA(U1, Bul[1], aU);                                                  \
    ffrag aH = MFMA(H0, Bhh[0], zerof);                                         \
    aH = MFMA(H1, Bhh[1], aH);                                                  \
    aH = MFMA(H0, Bhl[0], aH);                                                  \
    aH = MFMA(H1, Bhl[1], aH);                                                  \
    scW[0]        = aU[0] + aH[0];                                              \
    scW[SROW]     = aU[1] + aH[1];                                              \
    scW[2 * SROW] = aU[2] + aH[2];                                              \
    scW[3 * SROW] = aU[3] + aH[3];                                              \
    if (L0PART) {                                                               \
      ffrag aA = MFMA(U0, B0h[0], bias0f);                                      \
      aA = MFMA(U1, B0h[1], aA);                                                \
      aA = MFMA(U0, B0l[0], aA);                                                \
      aA = MFMA(U1, B0l[1], aA);                                                \
      sdW[0] = aA[0]; sdW[SROW] = aA[1];                                        \
      sdW[2 * SROW] = aA[2]; sdW[3 * SROW] = aA[3];                             \
    }                                                                           \
    if (!LASTR) {                                                               \
      const float4 ghi = *(const float4*)srd;                                   \
      const float4 glo = *(const float4*)(srd + 8 * SROW);                      \
      const float gi = fmaf(wx8a[0], x8v, ghi.x + glo.x);                       \
      const float gf = fmaf(wx8a[1], x8v, ghi.y + glo.y);                       \
      const float gg = fmaf(wx8a[2], x8v, ghi.z + glo.z);                       \
      const float go = fmaf(wx8a[3], x8v, ghi.w + glo.w);                       \
      const float iv = sigm_f(gi), fv = sigm_f(gf);                             \
      const float gv = tanh_f(gg), ov = sigm_f(go);                             \
      cst = fmaf(fv, cst, iv * gv);                                             \
      const float hv = ov * tanh_f(cst);                                        \
      short hs, hl; split_bf16(hv, hs, hl);                                     \
      short* hb = (RR == 0) ? hst0 : hst1;                                      \
      hb[0] = hs; hb[64] = hl;                                                  \
    } else if (half == 0) {                                                     \
      const float4 ghi = *(const float4*)srd;                                   \
      const float4 glo = *(const float4*)(srd + 8 * SROW);                      \
      const float gi = ghi.x + glo.x;                                           \
      const float gf = ghi.y + glo.y;                                           \
      const float gg = ghi.z + glo.z;                                           \
      const float go = ghi.w + glo.w;                                           \
      const float iv = sigm_f(gi), fv = sigm_f(gf);                             \
      const float gv = tanh_f(gg), ov = sigm_f(go);                             \
      cst = fmaf(fv, cst, iv * gv);                                             \
      sF[bq * H + aj] = ov * tanh_f(cst);                                       \
    }                                                                           \
    if (XSTG) {                                                                 \
      if (w == 0) {                                                             \
        const float xa = xps[0], xb = xps[1];                                   \
        if (half) {                                                             \
          short ah, al2, bh, bl2;                                               \
          split_bf16(xa, ah, al2); split_bf16(xb, bh, bl2);                     \
          short* xb_ = (RR == 0) ? xst0 : xst1;                                 \
          *(uint32_t*)xb_        = (uint16_t)ah  | ((uint32_t)(uint16_t)bh  << 16); \
          *(uint32_t*)(xb_ + 64) = (uint16_t)al2 | ((uint32_t)(uint16_t)bl2 << 16); \
        }                                                                       \
      }                                                                         \
      xps += IN0;                                                               \
    }                                                                           \
    __syncthreads();                                                            \
  }

  // regions 0..509 (255 unrolled pairs), then 510 (full, no staging), then 511
  for (int it = 0; it < 255; ++it) {
    REGION(0, 1, 1, 0)
    REGION(1, 1, 1, 0)
  }
  REGION(0, 1, 0, 0)
  REGION(1, 0, 0, 1)
#undef REGION

  // ---- FC head on final h1 ----
  if (tid < 28 * BG) {
    const int m  = tid >> 3;
    const int bb = tid & 7;
    float acc = fc1_b[m];
    const float4* w4 = (const float4*)(fc1_w + m * H);
    const float4* h4 = (const float4*)(sF + bb * H);
    #pragma unroll
    for (int qq = 0; qq < H / 4; ++qq) {
      const float4 wv4 = w4[qq], hv4 = h4[qq];
      acc = fmaf(wv4.x, hv4.x, acc);
      acc = fmaf(wv4.y, hv4.y, acc);
      acc = fmaf(wv4.z, hv4.z, acc);
      acc = fmaf(wv4.w, hv4.w, acc);
    }
    sY[bb * 28 + m] = fmaxf(acc, 0.0f);
  }
  __syncthreads();
  if (tid < BG) {
    float acc = fc2_b[0];
    #pragma unroll
    for (int m = 0; m < 28; ++m)
      acc = fmaf(fc2_w[m], sY[tid * 28 + m], acc);
    out[blockIdx.x * BG + tid] = acc;
  }
}

extern "C" void kernel_launch(void* const* d_in, const int* in_sizes, int n_in,
                              void* d_out, int out_size, void* d_ws, size_t ws_size,
                              hipStream_t stream)
{
  const float* x     = (const float*)d_in[0];
  const float* w_ih0 = (const float*)d_in[1];
  const float* w_hh0 = (const float*)d_in[2];
  const float* b_ih0 = (const float*)d_in[3];
  const float* b_hh0 = (const float*)d_in[4];
  const float* w_ih1 = (const float*)d_in[5];
  const float* w_hh1 = (const float*)d_in[6];
  const float* b_ih1 = (const float*)d_in[7];
  const float* b_hh1 = (const float*)d_in[8];
  const float* fc1_w = (const float*)d_in[9];
  const float* fc1_b = (const float*)d_in[10];
  const float* fc2_w = (const float*)d_in[11];
  const float* fc2_b = (const float*)d_in[12];
  float* out = (float*)d_out;

  lstm_mfma4<<<NBLK, NTH, 0, stream>>>(
      x, w_ih0, w_hh0, b_ih0, b_hh0, w_ih1, w_hh1, b_ih1, b_hh1,
      fc1_w, fc1_b, fc2_w, fc2_b, out);
}